// Round 2
// baseline (661.345 us; speedup 1.0000x reference)
//
#include <hip/hip_runtime.h>
#include <hip/hip_bf16.h>

#define N_ 20000
#define E_ 320000
#define B_ 64

typedef __attribute__((ext_vector_type(8))) short short8;
typedef __attribute__((ext_vector_type(4))) float f4;
typedef __attribute__((ext_vector_type(4))) unsigned int u4;
typedef __attribute__((ext_vector_type(4))) unsigned short us4;

union U8 { short s[8]; unsigned short us[8]; short8 v; u4 u; };

__device__ __forceinline__ unsigned short f2bs(float f) {
    unsigned int u = __float_as_uint(f);
    unsigned int r = u + 0x7FFFu + ((u >> 16) & 1u);  // round-to-nearest-even
    return (unsigned short)(r >> 16);
}

#define MFMA_B16(a, b, c) __builtin_amdgcn_mfma_f32_16x16x32_bf16(a, b, c, 0, 0, 0)

__device__ __constant__ int c_IDX[36] = {
    0,1,2,3,4,5, 1,6,7,8,9,10, 2,7,11,12,13,14,
    3,8,12,15,16,17, 4,9,13,16,18,19, 5,10,14,17,19,20};

// ---------------- init: x = node_attrs*embed_W + embed_b ; agg = 0 ----------------
__global__ __launch_bounds__(256) void k_init_x(const float* __restrict__ na,
                                                const float* __restrict__ eW,
                                                const float* __restrict__ eb,
                                                float* __restrict__ x, float* __restrict__ agg) {
    int tid = blockIdx.x * 256 + threadIdx.x;  // N_*32 exact
    int n = tid >> 5, c = tid & 31;
    x[tid] = na[n] * eW[c] + eb[c];
    agg[tid] = 0.f;
}

// ---------------- edge features: [vx,vy,vz,len,attr,0,0,0] packed as bf16 ----------------
__global__ __launch_bounds__(256) void k_edge_prep(const float* __restrict__ pos,
                                                   const float* __restrict__ shifts,
                                                   const float* __restrict__ eattr,
                                                   const int* __restrict__ eidx,
                                                   unsigned short* __restrict__ efp) {
    int e = blockIdx.x * 256 + threadIdx.x;  // E_ exact
    int s = eidx[e], d = eidx[E_ + e];
    float vx = pos[d * 3 + 0] - pos[s * 3 + 0] + shifts[e * 3 + 0];
    float vy = pos[d * 3 + 1] - pos[s * 3 + 1] + shifts[e * 3 + 1];
    float vz = pos[d * 3 + 2] - pos[s * 3 + 2] + shifts[e * 3 + 2];
    float ln = sqrtf(vx * vx + vy * vy + vz * vz);
    U8 o;
    o.us[0] = f2bs(vx); o.us[1] = f2bs(vy); o.us[2] = f2bs(vz);
    o.us[3] = f2bs(ln); o.us[4] = f2bs(eattr[e]);
    o.us[5] = 0; o.us[6] = 0; o.us[7] = 0;
    *(u4*)(efp + (size_t)e * 8) = o.u;
}

// ---------------- repack e_W3 (fp32) into bf16 A-fragment order ----------------
// frag layout: A[m=lane&15][k=(lane>>4)*8+j] = W3[k][t*16+m]
__global__ __launch_bounds__(256) void k_repack(const float* __restrict__ w3,
                                                unsigned short* __restrict__ w3r) {
    int tid = blockIdx.x * 256 + threadIdx.x;  // 3*64*64 = 12288 exact
    int l = tid & 63, t2 = (tid >> 6) & 63, i = tid >> 12;
    int q = l >> 4, m = l & 15;
    U8 o;
    for (int j = 0; j < 8; ++j) {
        int k = q * 8 + j;
        o.us[j] = f2bs(w3[(i * 32 + k) * 1024 + t2 * 16 + m]);
    }
    *(u4*)(w3r + (size_t)tid * 8) = o.u;
}

__global__ __launch_bounds__(256) void k_zero_pool(float* __restrict__ pooled, int* __restrict__ cnt) {
    int tid = blockIdx.x * 256 + threadIdx.x;
    if (tid < 2048) pooled[tid] = 0.f;
    else if (tid < 2112) cnt[tid - 2048] = 0;
}

// ---------------- main edge kernel: one layer ----------------
__global__ __launch_bounds__(256) void k_edge(
    const unsigned short* __restrict__ efp, const int* __restrict__ eidx,
    const float* __restrict__ x, float* __restrict__ agg,
    const float* __restrict__ w1, const float* __restrict__ b1,
    const float* __restrict__ w2, const float* __restrict__ b2,
    const unsigned short* __restrict__ w3r, const float* __restrict__ b3) {
    __shared__ float s_b3[1024];
    __shared__ __align__(16) unsigned short s_h[4][640];   // per-wave transpose buf, row stride 40
    __shared__ __align__(16) float s_x[4][2][576];         // per-wave x tiles, row stride 36

    const int t = threadIdx.x;
    for (int k = t; k < 1024; k += 256) s_b3[k] = b3[k];

    const int wave = t >> 6, lane = t & 63;
    const int q = lane >> 4, e = lane & 15;
    const int ebase = (blockIdx.x * 4 + wave) * 32;

    // stage x[src] tiles (fp32), row stride 36 to avoid bank conflicts
    for (int g = 0; g < 2; ++g) {
        int srce = eidx[ebase + g * 16 + e];
        const float* xp = x + srce * 32 + q * 8;
        f4 xa = *(const f4*)xp;
        f4 xb = *(const f4*)(xp + 4);
        float* dp = &s_x[wave][g][e * 36 + q * 8];
        *(f4*)dp = xa;
        *(f4*)(dp + 4) = xb;
    }

    // loop-invariant W1^T / W2^T fragments (bf16) + bias regs (fp32)
    U8 w1f[2], w2f[2];
    float b1v[2][4], b2v[2][4];
    for (int tau = 0; tau < 2; ++tau) {
        for (int j = 0; j < 8; ++j) {
            int k = q * 8 + j;
            w1f[tau].us[j] = (k < 5) ? f2bs(w1[k * 32 + tau * 16 + e]) : (unsigned short)0;
            w2f[tau].us[j] = f2bs(w2[k * 32 + tau * 16 + e]);
        }
        for (int r = 0; r < 4; ++r) {
            b1v[tau][r] = b1[tau * 16 + q * 4 + r];
            b2v[tau][r] = b2[tau * 16 + q * 4 + r];
        }
    }

    const f4 z4 = {0.f, 0.f, 0.f, 0.f};
    short8 h2f[2];

    __syncthreads();

    for (int g = 0; g < 2; ++g) {
        // ef B-fragment: only q==0 lanes carry data (5 real dims + 3 zero pads)
        U8 ef;
        if (q == 0) ef.u = *(const u4*)(efp + (size_t)(ebase + g * 16 + e) * 8);
        else { u4 zz = {0u, 0u, 0u, 0u}; ef.u = zz; }

        f4 c0 = MFMA_B16(w1f[0].v, ef.v, z4);
        f4 c1 = MFMA_B16(w1f[1].v, ef.v, z4);
        us4 pk;
        for (int r = 0; r < 4; ++r) pk[r] = f2bs(fmaxf(c0[r] + b1v[0][r], 0.f));
        *(us4*)&s_h[wave][e * 40 + q * 4] = pk;
        for (int r = 0; r < 4; ++r) pk[r] = f2bs(fmaxf(c1[r] + b1v[1][r], 0.f));
        *(us4*)&s_h[wave][e * 40 + 16 + q * 4] = pk;
        __syncthreads();
        short8 h1f = *(const short8*)&s_h[wave][e * 40 + q * 8];
        c0 = MFMA_B16(w2f[0].v, h1f, z4);
        c1 = MFMA_B16(w2f[1].v, h1f, z4);
        __syncthreads();
        for (int r = 0; r < 4; ++r) pk[r] = f2bs(fmaxf(c0[r] + b2v[0][r], 0.f));
        *(us4*)&s_h[wave][e * 40 + q * 4] = pk;
        for (int r = 0; r < 4; ++r) pk[r] = f2bs(fmaxf(c1[r] + b2v[1][r], 0.f));
        *(us4*)&s_h[wave][e * 40 + 16 + q * 4] = pk;
        __syncthreads();
        h2f[g] = *(const short8*)&s_h[wave][e * 40 + q * 8];
        __syncthreads();
    }

    // main loop: for each h, D = W3^T-frag * h2-frag + b3 (C-init),
    // then msg += x[src][h] * relu(D)
    f4 macc[2][2];
    macc[0][0] = z4; macc[0][1] = z4; macc[1][0] = z4; macc[1][1] = z4;

    for (int h = 0; h < 32; ++h) {
        short8 a0 = *(const short8*)(w3r + h * 1024 + lane * 8);
        short8 a1 = *(const short8*)(w3r + h * 1024 + 512 + lane * 8);
        f4 ci0 = *(const f4*)&s_b3[h * 32 + q * 4];
        f4 ci1 = *(const f4*)&s_b3[h * 32 + 16 + q * 4];
        for (int g = 0; g < 2; ++g) {
            f4 d0 = MFMA_B16(a0, h2f[g], ci0);
            f4 d1 = MFMA_B16(a1, h2f[g], ci1);
            float xv = s_x[wave][g][e * 36 + h];
            for (int r = 0; r < 4; ++r) {
                macc[g][0][r] += xv * fmaxf(d0[r], 0.f);
                macc[g][1][r] += xv * fmaxf(d1[r], 0.f);
            }
        }
    }

    // scatter-add into agg[dst][k], k = p*16 + q*4 + r
    for (int g = 0; g < 2; ++g) {
        int dste = eidx[E_ + ebase + g * 16 + e];
        float* ap = agg + dste * 32 + q * 4;
        for (int p = 0; p < 2; ++p)
            for (int r = 0; r < 4; ++r)
                atomicAdd(ap + p * 16 + r, macc[g][p][r]);
    }
}

// ---------------- node update: x += relu(agg + conv_b); agg = 0 ----------------
__global__ __launch_bounds__(256) void k_node(float* __restrict__ x, float* __restrict__ agg,
                                              const float* __restrict__ cb) {
    int tid = blockIdx.x * 256 + threadIdx.x;
    int c = tid & 31;
    float a = agg[tid] + cb[c];
    x[tid] += fmaxf(a, 0.f);
    agg[tid] = 0.f;
}

// ---------------- batch pooling ----------------
__global__ __launch_bounds__(256) void k_pool(const float* __restrict__ x, const int* __restrict__ batch,
                                              float* __restrict__ pooled, int* __restrict__ cnt) {
    int tid = blockIdx.x * 256 + threadIdx.x;
    int n = tid >> 5, c = tid & 31;
    int b = batch[n];
    atomicAdd(&pooled[b * 32 + c], x[tid]);
    if (c == 0) atomicAdd(&cnt[b], 1);
}

// ---------------- head MLP + IDX gather ----------------
__device__ __forceinline__ float selu_(float v) {
    return 1.0507009873554805f * (v > 0.f ? v : 1.6732632423543772f * (expf(v) - 1.f));
}

__global__ __launch_bounds__(128) void k_head(const float* __restrict__ pooled, const int* __restrict__ cnt,
                                              const float* __restrict__ W1, const float* __restrict__ b1,
                                              const float* __restrict__ W2, const float* __restrict__ b2,
                                              const float* __restrict__ W3, const float* __restrict__ b3,
                                              const float* __restrict__ W4, const float* __restrict__ b4,
                                              float* __restrict__ out) {
    __shared__ float s0[32], s1[128], s2[64], s3[32], s4[21];
    int b = blockIdx.x, t = threadIdx.x;
    if (t < 32) s0[t] = pooled[b * 32 + t] / fmaxf((float)cnt[b], 1.f);
    __syncthreads();
    {
        float a = b1[t];
        for (int c = 0; c < 32; ++c) a += s0[c] * W1[c * 128 + t];
        s1[t] = selu_(a);
    }
    __syncthreads();
    if (t < 64) {
        float a = b2[t];
        for (int c = 0; c < 128; ++c) a += s1[c] * W2[c * 64 + t];
        s2[t] = selu_(a);
    }
    __syncthreads();
    if (t < 32) {
        float a = b3[t];
        for (int c = 0; c < 64; ++c) a += s2[c] * W3[c * 32 + t];
        s3[t] = selu_(a);
    }
    __syncthreads();
    if (t < 21) {
        float a = b4[t];
        for (int c = 0; c < 32; ++c) a += s3[c] * W4[c * 21 + t];
        s4[t] = a;
    }
    __syncthreads();
    if (t < 36) out[b * 36 + t] = s4[c_IDX[t]];
}

extern "C" void kernel_launch(void* const* d_in, const int* in_sizes, int n_in,
                              void* d_out, int out_size, void* d_ws, size_t ws_size,
                              hipStream_t stream) {
    const float* na     = (const float*)d_in[0];
    const float* pos    = (const float*)d_in[1];
    const float* shifts = (const float*)d_in[2];
    const float* eattr  = (const float*)d_in[3];
    const int*   eidx   = (const int*)d_in[4];
    const int*   batch  = (const int*)d_in[5];
    const float* embW   = (const float*)d_in[6];
    const float* embB   = (const float*)d_in[7];
    const float* eW1    = (const float*)d_in[8];
    const float* eb1    = (const float*)d_in[9];
    const float* eW2    = (const float*)d_in[10];
    const float* eb2    = (const float*)d_in[11];
    const float* eW3    = (const float*)d_in[12];
    const float* eb3    = (const float*)d_in[13];
    const float* cvb    = (const float*)d_in[14];
    const float* hW1    = (const float*)d_in[15];
    const float* hb1    = (const float*)d_in[16];
    const float* hW2    = (const float*)d_in[17];
    const float* hb2    = (const float*)d_in[18];
    const float* hW3    = (const float*)d_in[19];
    const float* hb3    = (const float*)d_in[20];
    const float* hW4    = (const float*)d_in[21];
    const float* hb4    = (const float*)d_in[22];

    char* ws = (char*)d_ws;
    float* x      = (float*)ws;                   // 640000 f32
    float* agg    = x + 640000;                   // 640000 f32
    float* pooled = agg + 640000;                 // 2048 f32
    int*   cnt    = (int*)(pooled + 2048);        // 64 i32
    unsigned short* efp = (unsigned short*)(cnt + 64);   // E_*8 bf16
    unsigned short* w3r = efp + (size_t)E_ * 8;          // 98304 bf16

    k_init_x<<<2500, 256, 0, stream>>>(na, embW, embB, x, agg);
    k_edge_prep<<<1250, 256, 0, stream>>>(pos, shifts, eattr, eidx, efp);
    k_repack<<<48, 256, 0, stream>>>(eW3, w3r);
    k_zero_pool<<<9, 256, 0, stream>>>(pooled, cnt);

    for (int i = 0; i < 3; ++i) {
        k_edge<<<2500, 256, 0, stream>>>(efp, eidx, x, agg,
                                         eW1 + i * 160, eb1 + i * 32,
                                         eW2 + i * 1024, eb2 + i * 32,
                                         w3r + i * 32768, eb3 + i * 1024);
        k_node<<<2500, 256, 0, stream>>>(x, agg, cvb + i * 32);
    }

    k_pool<<<2500, 256, 0, stream>>>(x, batch, pooled, cnt);
    k_head<<<64, 128, 0, stream>>>(pooled, cnt, hW1, hb1, hW2, hb2, hW3, hb3, hW4, hb4,
                                   (float*)d_out);
}

// Round 3
// 528.817 us; speedup vs baseline: 1.2506x; 1.2506x over previous
//
#include <hip/hip_runtime.h>
#include <hip/hip_bf16.h>

#define N_ 20000
#define E_ 320000
#define B_ 64

typedef __attribute__((ext_vector_type(8))) short short8;
typedef __attribute__((ext_vector_type(4))) float f4;
typedef __attribute__((ext_vector_type(4))) unsigned int u4;
typedef __attribute__((ext_vector_type(4))) unsigned short us4;

union U8 { short s[8]; unsigned short us[8]; short8 v; u4 u; };

__device__ __forceinline__ float bs2f(unsigned short s) {
    return __uint_as_float(((unsigned int)s) << 16);
}
__device__ __forceinline__ unsigned short f2bs(float f) {
    unsigned int u = __float_as_uint(f);
    unsigned int r = u + 0x7FFFu + ((u >> 16) & 1u);  // round-to-nearest-even
    return (unsigned short)(r >> 16);
}

#define MFMA_B16(a, b, c) __builtin_amdgcn_mfma_f32_16x16x32_bf16(a, b, c, 0, 0, 0)

__device__ __constant__ int c_IDX[36] = {
    0,1,2,3,4,5, 1,6,7,8,9,10, 2,7,11,12,13,14,
    3,8,12,15,16,17, 4,9,13,16,18,19, 5,10,14,17,19,20};

// ---------------- init: x = node_attrs*embed_W + embed_b ; zero aux ----------------
__global__ __launch_bounds__(256) void k_init_x(const float* __restrict__ na,
                                                const float* __restrict__ eW,
                                                const float* __restrict__ eb,
                                                float* __restrict__ x,
                                                int* __restrict__ aux, int aux_len) {
    int tid = blockIdx.x * 256 + threadIdx.x;  // N_*32 exact
    int n = tid >> 5, c = tid & 31;
    x[tid] = na[n] * eW[c] + eb[c];
    if (tid < aux_len) aux[tid] = 0;
}

// ---------------- edge features: [vx,vy,vz,len,attr,0,0,0] packed as bf16 ----------------
__global__ __launch_bounds__(256) void k_edge_prep(const float* __restrict__ pos,
                                                   const float* __restrict__ shifts,
                                                   const float* __restrict__ eattr,
                                                   const int* __restrict__ eidx,
                                                   unsigned short* __restrict__ efp) {
    int e = blockIdx.x * 256 + threadIdx.x;  // E_ exact
    int s = eidx[e], d = eidx[E_ + e];
    float vx = pos[d * 3 + 0] - pos[s * 3 + 0] + shifts[e * 3 + 0];
    float vy = pos[d * 3 + 1] - pos[s * 3 + 1] + shifts[e * 3 + 1];
    float vz = pos[d * 3 + 2] - pos[s * 3 + 2] + shifts[e * 3 + 2];
    float ln = sqrtf(vx * vx + vy * vy + vz * vz);
    U8 o;
    o.us[0] = f2bs(vx); o.us[1] = f2bs(vy); o.us[2] = f2bs(vz);
    o.us[3] = f2bs(ln); o.us[4] = f2bs(eattr[e]);
    o.us[5] = 0; o.us[6] = 0; o.us[7] = 0;
    *(u4*)(efp + (size_t)e * 8) = o.u;
}

// ---------------- repack e_W3 (fp32) into bf16 A-fragment order ----------------
__global__ __launch_bounds__(256) void k_repack(const float* __restrict__ w3,
                                                unsigned short* __restrict__ w3r) {
    int tid = blockIdx.x * 256 + threadIdx.x;  // 3*64*64 = 12288 exact
    int l = tid & 63, t2 = (tid >> 6) & 63, i = tid >> 12;
    int q = l >> 4, m = l & 15;
    U8 o;
    for (int j = 0; j < 8; ++j) {
        int k = q * 8 + j;
        o.us[j] = f2bs(w3[(i * 32 + k) * 1024 + t2 * 16 + m]);
    }
    *(u4*)(w3r + (size_t)tid * 8) = o.u;
}

__global__ __launch_bounds__(256) void k_zero_pool(float* __restrict__ pooled, int* __restrict__ cnt) {
    int tid = blockIdx.x * 256 + threadIdx.x;
    if (tid < 2048) pooled[tid] = 0.f;
    else if (tid < 2112) cnt[tid - 2048] = 0;
}

// ---------------- CSR build ----------------
__global__ __launch_bounds__(256) void k_hist(const int* __restrict__ eidx, int* __restrict__ deg) {
    int e = blockIdx.x * 256 + threadIdx.x;
    atomicAdd(&deg[eidx[E_ + e]], 1);
}

// single-block exclusive scan over deg[0..N_) -> off, cur ; off[N_]=E_
__global__ __launch_bounds__(1024) void k_scan(const int* __restrict__ deg,
                                               int* __restrict__ off, int* __restrict__ cur) {
    __shared__ int sh[1024];
    int t = threadIdx.x;
    int base = t * 20;  // 1024*20 = 20480 >= N_
    int loc[20]; int s = 0;
    for (int k = 0; k < 20; ++k) {
        int i = base + k;
        int v = (i < N_) ? deg[i] : 0;
        loc[k] = s; s += v;
    }
    sh[t] = s;
    __syncthreads();
    for (int d = 1; d < 1024; d <<= 1) {
        int val = (t >= d) ? sh[t - d] : 0;
        __syncthreads();
        sh[t] += val;
        __syncthreads();
    }
    int excl = sh[t] - s;
    for (int k = 0; k < 20; ++k) {
        int i = base + k;
        if (i < N_) { int o = excl + loc[k]; off[i] = o; cur[i] = o; }
    }
    if (t == 1023) off[N_] = sh[1023];
}

__global__ __launch_bounds__(256) void k_fill(const int* __restrict__ eidx,
                                              int* __restrict__ cur, int* __restrict__ perm) {
    int e = blockIdx.x * 256 + threadIdx.x;
    int d = eidx[E_ + e];
    int p = atomicAdd(&cur[d], 1);
    perm[p] = e;
}

// ---------------- main edge kernel: one layer ----------------
// STORE=true: write bf16 msg rows. STORE=false: atomicAdd into fp32 agg (fallback).
template <bool STORE>
__global__ __launch_bounds__(256) void k_edge(
    const unsigned short* __restrict__ efp, const int* __restrict__ eidx,
    const float* __restrict__ x, float* __restrict__ agg, unsigned short* __restrict__ msg,
    const float* __restrict__ w1, const float* __restrict__ b1,
    const float* __restrict__ w2, const float* __restrict__ b2,
    const unsigned short* __restrict__ w3r, const float* __restrict__ b3) {
    __shared__ float s_b3[1024];
    __shared__ __align__(16) unsigned short s_h[4][640];   // per-wave transpose buf, row stride 40
    __shared__ __align__(16) float s_x[4][2][576];         // per-wave x tiles, row stride 36

    const int t = threadIdx.x;
    for (int k = t; k < 1024; k += 256) s_b3[k] = b3[k];

    const int wave = t >> 6, lane = t & 63;
    const int q = lane >> 4, e = lane & 15;
    const int ebase = (blockIdx.x * 4 + wave) * 32;

    // stage x[src] tiles (fp32), row stride 36 to avoid bank conflicts
    for (int g = 0; g < 2; ++g) {
        int srce = eidx[ebase + g * 16 + e];
        const float* xp = x + srce * 32 + q * 8;
        f4 xa = *(const f4*)xp;
        f4 xb = *(const f4*)(xp + 4);
        float* dp = &s_x[wave][g][e * 36 + q * 8];
        *(f4*)dp = xa;
        *(f4*)(dp + 4) = xb;
    }

    // loop-invariant W1^T / W2^T fragments (bf16) + bias regs (fp32)
    U8 w1f[2], w2f[2];
    float b1v[2][4], b2v[2][4];
    for (int tau = 0; tau < 2; ++tau) {
        for (int j = 0; j < 8; ++j) {
            int k = q * 8 + j;
            w1f[tau].us[j] = (k < 5) ? f2bs(w1[k * 32 + tau * 16 + e]) : (unsigned short)0;
            w2f[tau].us[j] = f2bs(w2[k * 32 + tau * 16 + e]);
        }
        for (int r = 0; r < 4; ++r) {
            b1v[tau][r] = b1[tau * 16 + q * 4 + r];
            b2v[tau][r] = b2[tau * 16 + q * 4 + r];
        }
    }

    const f4 z4 = {0.f, 0.f, 0.f, 0.f};
    short8 h2f[2];

    __syncthreads();

    for (int g = 0; g < 2; ++g) {
        // ef B-fragment: only q==0 lanes carry data (5 real dims + 3 zero pads)
        U8 ef;
        if (q == 0) ef.u = *(const u4*)(efp + (size_t)(ebase + g * 16 + e) * 8);
        else { u4 zz = {0u, 0u, 0u, 0u}; ef.u = zz; }

        f4 c0 = MFMA_B16(w1f[0].v, ef.v, z4);
        f4 c1 = MFMA_B16(w1f[1].v, ef.v, z4);
        us4 pk;
        for (int r = 0; r < 4; ++r) pk[r] = f2bs(fmaxf(c0[r] + b1v[0][r], 0.f));
        *(us4*)&s_h[wave][e * 40 + q * 4] = pk;
        for (int r = 0; r < 4; ++r) pk[r] = f2bs(fmaxf(c1[r] + b1v[1][r], 0.f));
        *(us4*)&s_h[wave][e * 40 + 16 + q * 4] = pk;
        __syncthreads();
        short8 h1f = *(const short8*)&s_h[wave][e * 40 + q * 8];
        c0 = MFMA_B16(w2f[0].v, h1f, z4);
        c1 = MFMA_B16(w2f[1].v, h1f, z4);
        __syncthreads();
        for (int r = 0; r < 4; ++r) pk[r] = f2bs(fmaxf(c0[r] + b2v[0][r], 0.f));
        *(us4*)&s_h[wave][e * 40 + q * 4] = pk;
        for (int r = 0; r < 4; ++r) pk[r] = f2bs(fmaxf(c1[r] + b2v[1][r], 0.f));
        *(us4*)&s_h[wave][e * 40 + 16 + q * 4] = pk;
        __syncthreads();
        h2f[g] = *(const short8*)&s_h[wave][e * 40 + q * 8];
        __syncthreads();
    }

    // main loop: for each h, D = W3^T-frag * h2-frag + b3 (C-init),
    // then msg += x[src][h] * relu(D)
    f4 macc[2][2];
    macc[0][0] = z4; macc[0][1] = z4; macc[1][0] = z4; macc[1][1] = z4;

    for (int h = 0; h < 32; ++h) {
        short8 a0 = *(const short8*)(w3r + h * 1024 + lane * 8);
        short8 a1 = *(const short8*)(w3r + h * 1024 + 512 + lane * 8);
        f4 ci0 = *(const f4*)&s_b3[h * 32 + q * 4];
        f4 ci1 = *(const f4*)&s_b3[h * 32 + 16 + q * 4];
        for (int g = 0; g < 2; ++g) {
            f4 d0 = MFMA_B16(a0, h2f[g], ci0);
            f4 d1 = MFMA_B16(a1, h2f[g], ci1);
            float xv = s_x[wave][g][e * 36 + h];
            for (int r = 0; r < 4; ++r) {
                macc[g][0][r] += xv * fmaxf(d0[r], 0.f);
                macc[g][1][r] += xv * fmaxf(d1[r], 0.f);
            }
        }
    }

    if (STORE) {
        // plain coalesced bf16 store: msg[edge][k], k = p*16 + q*4 + r
        for (int g = 0; g < 2; ++g) {
            unsigned short* mp = msg + (size_t)(ebase + g * 16 + e) * 32 + q * 4;
            for (int p = 0; p < 2; ++p) {
                us4 pk;
                for (int r = 0; r < 4; ++r) pk[r] = f2bs(macc[g][p][r]);
                *(us4*)(mp + p * 16) = pk;
            }
        }
    } else {
        for (int g = 0; g < 2; ++g) {
            int dste = eidx[E_ + ebase + g * 16 + e];
            float* ap = agg + dste * 32 + q * 4;
            for (int p = 0; p < 2; ++p)
                for (int r = 0; r < 4; ++r)
                    atomicAdd(ap + p * 16 + r, macc[g][p][r]);
        }
    }
}

// ---------------- gather: x += relu(segment_sum(msg) + conv_b) ----------------
__global__ __launch_bounds__(256) void k_gather(const unsigned short* __restrict__ msg,
                                                const int* __restrict__ off,
                                                const int* __restrict__ perm,
                                                const float* __restrict__ cb,
                                                float* __restrict__ x) {
    int tid = blockIdx.x * 256 + threadIdx.x;  // N_*32 exact
    int n = tid >> 5, c = tid & 31;
    int j0 = off[n], j1 = off[n + 1];
    float a = cb[c];
    for (int j = j0; j < j1; ++j) {
        int e = perm[j];
        a += bs2f(msg[(size_t)e * 32 + c]);
    }
    x[tid] += fmaxf(a, 0.f);
}

// ---------------- node update (fallback path): x += relu(agg + conv_b); agg = 0 ----------------
__global__ __launch_bounds__(256) void k_node(float* __restrict__ x, float* __restrict__ agg,
                                              const float* __restrict__ cb) {
    int tid = blockIdx.x * 256 + threadIdx.x;
    int c = tid & 31;
    float a = agg[tid] + cb[c];
    x[tid] += fmaxf(a, 0.f);
    agg[tid] = 0.f;
}

// ---------------- batch pooling ----------------
__global__ __launch_bounds__(256) void k_pool(const float* __restrict__ x, const int* __restrict__ batch,
                                              float* __restrict__ pooled, int* __restrict__ cnt) {
    int tid = blockIdx.x * 256 + threadIdx.x;
    int n = tid >> 5, c = tid & 31;
    int b = batch[n];
    atomicAdd(&pooled[b * 32 + c], x[tid]);
    if (c == 0) atomicAdd(&cnt[b], 1);
}

// ---------------- head MLP + IDX gather ----------------
__device__ __forceinline__ float selu_(float v) {
    return 1.0507009873554805f * (v > 0.f ? v : 1.6732632423543772f * (expf(v) - 1.f));
}

__global__ __launch_bounds__(128) void k_head(const float* __restrict__ pooled, const int* __restrict__ cnt,
                                              const float* __restrict__ W1, const float* __restrict__ b1,
                                              const float* __restrict__ W2, const float* __restrict__ b2,
                                              const float* __restrict__ W3, const float* __restrict__ b3,
                                              const float* __restrict__ W4, const float* __restrict__ b4,
                                              float* __restrict__ out) {
    __shared__ float s0[32], s1[128], s2[64], s3[32], s4[21];
    int b = blockIdx.x, t = threadIdx.x;
    if (t < 32) s0[t] = pooled[b * 32 + t] / fmaxf((float)cnt[b], 1.f);
    __syncthreads();
    {
        float a = b1[t];
        for (int c = 0; c < 32; ++c) a += s0[c] * W1[c * 128 + t];
        s1[t] = selu_(a);
    }
    __syncthreads();
    if (t < 64) {
        float a = b2[t];
        for (int c = 0; c < 128; ++c) a += s1[c] * W2[c * 64 + t];
        s2[t] = selu_(a);
    }
    __syncthreads();
    if (t < 32) {
        float a = b3[t];
        for (int c = 0; c < 64; ++c) a += s2[c] * W3[c * 32 + t];
        s3[t] = selu_(a);
    }
    __syncthreads();
    if (t < 21) {
        float a = b4[t];
        for (int c = 0; c < 32; ++c) a += s3[c] * W4[c * 21 + t];
        s4[t] = a;
    }
    __syncthreads();
    if (t < 36) out[b * 36 + t] = s4[c_IDX[t]];
}

extern "C" void kernel_launch(void* const* d_in, const int* in_sizes, int n_in,
                              void* d_out, int out_size, void* d_ws, size_t ws_size,
                              hipStream_t stream) {
    const float* na     = (const float*)d_in[0];
    const float* pos    = (const float*)d_in[1];
    const float* shifts = (const float*)d_in[2];
    const float* eattr  = (const float*)d_in[3];
    const int*   eidx   = (const int*)d_in[4];
    const int*   batch  = (const int*)d_in[5];
    const float* embW   = (const float*)d_in[6];
    const float* embB   = (const float*)d_in[7];
    const float* eW1    = (const float*)d_in[8];
    const float* eb1    = (const float*)d_in[9];
    const float* eW2    = (const float*)d_in[10];
    const float* eb2    = (const float*)d_in[11];
    const float* eW3    = (const float*)d_in[12];
    const float* eb3    = (const float*)d_in[13];
    const float* cvb    = (const float*)d_in[14];
    const float* hW1    = (const float*)d_in[15];
    const float* hb1    = (const float*)d_in[16];
    const float* hW2    = (const float*)d_in[17];
    const float* hb2    = (const float*)d_in[18];
    const float* hW3    = (const float*)d_in[19];
    const float* hb3    = (const float*)d_in[20];
    const float* hW4    = (const float*)d_in[21];
    const float* hb4    = (const float*)d_in[22];

    const size_t need_csr = (size_t)(640000 + 2048 + 64 + 20000 + 20004 + 20000 + 320000) * 4
                          + (size_t)E_ * 8 * 2 + 98304 * 2 + (size_t)E_ * 32 * 2;

    if (ws_size >= need_csr) {
        // ---------- CSR path: no device-scope fp32 atomics in the hot loop ----------
        char* ws = (char*)d_ws;
        float* x      = (float*)ws;                      // 640000 f32
        float* pooled = x + 640000;                      // 2048 f32
        int*   cnt    = (int*)(pooled + 2048);           // 64
        int*   deg    = cnt + 64;                        // 20000
        int*   off    = deg + 20000;                     // 20001 (pad to 20004)
        int*   cur    = off + 20004;                     // 20000
        int*   perm   = cur + 20000;                     // 320000
        unsigned short* efp = (unsigned short*)(perm + 320000);  // E_*8 bf16
        unsigned short* w3r = efp + (size_t)E_ * 8;              // 98304 bf16
        unsigned short* msg = w3r + 98304;                       // E_*32 bf16

        k_init_x<<<2500, 256, 0, stream>>>(na, embW, embB, x, deg, 20000);
        k_edge_prep<<<1250, 256, 0, stream>>>(pos, shifts, eattr, eidx, efp);
        k_repack<<<48, 256, 0, stream>>>(eW3, w3r);
        k_zero_pool<<<9, 256, 0, stream>>>(pooled, cnt);
        k_hist<<<1250, 256, 0, stream>>>(eidx, deg);
        k_scan<<<1, 1024, 0, stream>>>(deg, off, cur);
        k_fill<<<1250, 256, 0, stream>>>(eidx, cur, perm);

        for (int i = 0; i < 3; ++i) {
            k_edge<true><<<2500, 256, 0, stream>>>(efp, eidx, x, nullptr, msg,
                                                   eW1 + i * 160, eb1 + i * 32,
                                                   eW2 + i * 1024, eb2 + i * 32,
                                                   w3r + i * 32768, eb3 + i * 1024);
            k_gather<<<2500, 256, 0, stream>>>(msg, off, perm, cvb + i * 32, x);
        }

        k_pool<<<2500, 256, 0, stream>>>(x, batch, pooled, cnt);
        k_head<<<64, 128, 0, stream>>>(pooled, cnt, hW1, hb1, hW2, hb2, hW3, hb3, hW4, hb4,
                                       (float*)d_out);
    } else {
        // ---------- fallback: atomic scatter path (round-2 behavior) ----------
        char* ws = (char*)d_ws;
        float* x      = (float*)ws;                   // 640000 f32
        float* agg    = x + 640000;                   // 640000 f32
        float* pooled = agg + 640000;                 // 2048 f32
        int*   cnt    = (int*)(pooled + 2048);        // 64 i32
        unsigned short* efp = (unsigned short*)(cnt + 64);   // E_*8 bf16
        unsigned short* w3r = efp + (size_t)E_ * 8;          // 98304 bf16

        k_init_x<<<2500, 256, 0, stream>>>(na, embW, embB, x, (int*)agg, 0);
        // zero agg via a dedicated pass (reuse k_init_x aux path would need len 640000)
        hipMemsetAsync(agg, 0, 640000 * sizeof(float), stream);
        k_edge_prep<<<1250, 256, 0, stream>>>(pos, shifts, eattr, eidx, efp);
        k_repack<<<48, 256, 0, stream>>>(eW3, w3r);
        k_zero_pool<<<9, 256, 0, stream>>>(pooled, cnt);

        for (int i = 0; i < 3; ++i) {
            k_edge<false><<<2500, 256, 0, stream>>>(efp, eidx, x, agg, nullptr,
                                                    eW1 + i * 160, eb1 + i * 32,
                                                    eW2 + i * 1024, eb2 + i * 32,
                                                    w3r + i * 32768, eb3 + i * 1024);
            k_node<<<2500, 256, 0, stream>>>(x, agg, cvb + i * 32);
        }

        k_pool<<<2500, 256, 0, stream>>>(x, batch, pooled, cnt);
        k_head<<<64, 128, 0, stream>>>(pooled, cnt, hW1, hb1, hW2, hb2, hW3, hb3, hW4, hb4,
                                       (float*)d_out);
    }
}

// Round 4
// 496.987 us; speedup vs baseline: 1.3307x; 1.0640x over previous
//
#include <hip/hip_runtime.h>
#include <hip/hip_bf16.h>

#define N_ 20000
#define E_ 320000
#define B_ 64

typedef __attribute__((ext_vector_type(8))) short short8;
typedef __attribute__((ext_vector_type(4))) float f4;
typedef __attribute__((ext_vector_type(4))) unsigned int u4;
typedef __attribute__((ext_vector_type(4))) unsigned short us4;

union U8 { short s[8]; unsigned short us[8]; short8 v; u4 u; };

__device__ __forceinline__ float bs2f(unsigned short s) {
    return __uint_as_float(((unsigned int)s) << 16);
}
__device__ __forceinline__ unsigned short f2bs(float f) {
    unsigned int u = __float_as_uint(f);
    unsigned int r = u + 0x7FFFu + ((u >> 16) & 1u);  // round-to-nearest-even
    return (unsigned short)(r >> 16);
}

#define MFMA_B16(a, b, c) __builtin_amdgcn_mfma_f32_16x16x32_bf16(a, b, c, 0, 0, 0)

__device__ __constant__ int c_IDX[36] = {
    0,1,2,3,4,5, 1,6,7,8,9,10, 2,7,11,12,13,14,
    3,8,12,15,16,17, 4,9,13,16,18,19, 5,10,14,17,19,20};

// ---------------- init: x = node_attrs*embed_W + embed_b ; zero aux ints ----------------
__global__ __launch_bounds__(256) void k_init_x(const float* __restrict__ na,
                                                const float* __restrict__ eW,
                                                const float* __restrict__ eb,
                                                float* __restrict__ x,
                                                int* __restrict__ aux, int aux_len) {
    int tid = blockIdx.x * 256 + threadIdx.x;  // N_*32 exact
    int n = tid >> 5, c = tid & 31;
    x[tid] = na[n] * eW[c] + eb[c];
    if (tid < aux_len) aux[tid] = 0;
}

// ---------------- edge features: [vx,vy,vz,len,attr,0,0,0] packed as bf16 ----------------
__global__ __launch_bounds__(256) void k_edge_prep(const float* __restrict__ pos,
                                                   const float* __restrict__ shifts,
                                                   const float* __restrict__ eattr,
                                                   const int* __restrict__ eidx,
                                                   unsigned short* __restrict__ efp) {
    int e = blockIdx.x * 256 + threadIdx.x;  // E_ exact
    int s = eidx[e], d = eidx[E_ + e];
    float vx = pos[d * 3 + 0] - pos[s * 3 + 0] + shifts[e * 3 + 0];
    float vy = pos[d * 3 + 1] - pos[s * 3 + 1] + shifts[e * 3 + 1];
    float vz = pos[d * 3 + 2] - pos[s * 3 + 2] + shifts[e * 3 + 2];
    float ln = sqrtf(vx * vx + vy * vy + vz * vz);
    U8 o;
    o.us[0] = f2bs(vx); o.us[1] = f2bs(vy); o.us[2] = f2bs(vz);
    o.us[3] = f2bs(ln); o.us[4] = f2bs(eattr[e]);
    o.us[5] = 0; o.us[6] = 0; o.us[7] = 0;
    *(u4*)(efp + (size_t)e * 8) = o.u;
}

// ---------------- repack e_W3 (fp32) into bf16 A-fragment order ----------------
__global__ __launch_bounds__(256) void k_repack(const float* __restrict__ w3,
                                                unsigned short* __restrict__ w3r) {
    int tid = blockIdx.x * 256 + threadIdx.x;  // 3*64*64 = 12288 exact
    int l = tid & 63, t2 = (tid >> 6) & 63, i = tid >> 12;
    int q = l >> 4, m = l & 15;
    U8 o;
    for (int j = 0; j < 8; ++j) {
        int k = q * 8 + j;
        o.us[j] = f2bs(w3[(i * 32 + k) * 1024 + t2 * 16 + m]);
    }
    *(u4*)(w3r + (size_t)tid * 8) = o.u;
}

__global__ __launch_bounds__(256) void k_zero_pool(float* __restrict__ pooled, int* __restrict__ cnt) {
    int tid = blockIdx.x * 256 + threadIdx.x;
    if (tid < 2048) pooled[tid] = 0.f;
    else if (tid < 2112) cnt[tid - 2048] = 0;
}

// ---------------- node CSR build ----------------
__global__ __launch_bounds__(256) void k_hist(const int* __restrict__ eidx, int* __restrict__ deg) {
    int e = blockIdx.x * 256 + threadIdx.x;
    atomicAdd(&deg[eidx[E_ + e]], 1);
}

// single-block exclusive scan over deg[0..N_) -> off, cur ; off[N_]=E_
__global__ __launch_bounds__(1024) void k_scan(const int* __restrict__ deg,
                                               int* __restrict__ off, int* __restrict__ cur) {
    __shared__ int sh[1024];
    int t = threadIdx.x;
    int base = t * 20;  // 1024*20 = 20480 >= N_
    int loc[20]; int s = 0;
    for (int k = 0; k < 20; ++k) {
        int i = base + k;
        int v = (i < N_) ? deg[i] : 0;
        loc[k] = s; s += v;
    }
    sh[t] = s;
    __syncthreads();
    for (int d = 1; d < 1024; d <<= 1) {
        int val = (t >= d) ? sh[t - d] : 0;
        __syncthreads();
        sh[t] += val;
        __syncthreads();
    }
    int excl = sh[t] - s;
    for (int k = 0; k < 20; ++k) {
        int i = base + k;
        if (i < N_) { int o = excl + loc[k]; off[i] = o; cur[i] = o; }
    }
    if (t == 1023) off[N_] = sh[1023];
}

// rank[e] = slot of edge e within CSR order
__global__ __launch_bounds__(256) void k_fill(const int* __restrict__ eidx,
                                              int* __restrict__ cur, int* __restrict__ rank) {
    int e = blockIdx.x * 256 + threadIdx.x;
    int d = eidx[E_ + e];
    rank[e] = atomicAdd(&cur[d], 1);
}

// ---------------- batch CSR build ----------------
__global__ __launch_bounds__(256) void k_bhist(const int* __restrict__ batch, int* __restrict__ bcnt) {
    __shared__ int s[64];
    int t = threadIdx.x;
    if (t < 64) s[t] = 0;
    __syncthreads();
    int n = blockIdx.x * 256 + t;
    if (n < N_) atomicAdd(&s[batch[n]], 1);
    __syncthreads();
    if (t < 64 && s[t]) atomicAdd(&bcnt[t], s[t]);
}

__global__ __launch_bounds__(64) void k_bscan(const int* __restrict__ bcnt,
                                              int* __restrict__ boff, int* __restrict__ bcur) {
    __shared__ int sh[64];
    int t = threadIdx.x;
    int v = bcnt[t];
    sh[t] = v;
    __syncthreads();
    for (int d = 1; d < 64; d <<= 1) {
        int val = (t >= d) ? sh[t - d] : 0;
        __syncthreads();
        sh[t] += val;
        __syncthreads();
    }
    int excl = sh[t] - v;
    boff[t] = excl; bcur[t] = excl;
    if (t == 63) boff[64] = sh[63];
}

__global__ __launch_bounds__(256) void k_bfill(const int* __restrict__ batch,
                                               int* __restrict__ bcur, int* __restrict__ bperm) {
    int n = blockIdx.x * 256 + threadIdx.x;
    if (n < N_) {
        int p = atomicAdd(&bcur[batch[n]], 1);
        bperm[p] = n;
    }
}

// ---------------- main edge kernel: one layer, 64 edges/wave ----------------
// STORE=true: write bf16 msg rows at CSR rank. STORE=false: atomicAdd into fp32 agg.
template <bool STORE>
__global__ __launch_bounds__(256) void k_edge(
    const unsigned short* __restrict__ efp, const int* __restrict__ eidx,
    const int* __restrict__ rank,
    const float* __restrict__ x, float* __restrict__ agg, unsigned short* __restrict__ msg,
    const float* __restrict__ w1, const float* __restrict__ b1,
    const float* __restrict__ w2, const float* __restrict__ b2,
    const unsigned short* __restrict__ w3r, const float* __restrict__ b3) {
    __shared__ float s_b3[1024];
    __shared__ __align__(16) unsigned short s_h[4][640];   // per-wave transpose buf, row stride 40
    __shared__ __align__(16) float s_x[4][4][576];         // per-wave x tiles, row stride 36

    const int t = threadIdx.x;
    for (int k = t; k < 1024; k += 256) s_b3[k] = b3[k];

    const int wave = t >> 6, lane = t & 63;
    const int q = lane >> 4, e = lane & 15;
    const int ebase = (blockIdx.x * 4 + wave) * 64;

    // stage x[src] tiles (fp32), row stride 36 to avoid bank conflicts
    for (int g = 0; g < 4; ++g) {
        int srce = eidx[ebase + g * 16 + e];
        const float* xp = x + srce * 32 + q * 8;
        f4 xa = *(const f4*)xp;
        f4 xb = *(const f4*)(xp + 4);
        float* dp = &s_x[wave][g][e * 36 + q * 8];
        *(f4*)dp = xa;
        *(f4*)(dp + 4) = xb;
    }

    // loop-invariant W1^T / W2^T fragments (bf16) + bias regs (fp32)
    U8 w1f[2], w2f[2];
    float b1v[2][4], b2v[2][4];
    for (int tau = 0; tau < 2; ++tau) {
        for (int j = 0; j < 8; ++j) {
            int k = q * 8 + j;
            w1f[tau].us[j] = (k < 5) ? f2bs(w1[k * 32 + tau * 16 + e]) : (unsigned short)0;
            w2f[tau].us[j] = f2bs(w2[k * 32 + tau * 16 + e]);
        }
        for (int r = 0; r < 4; ++r) {
            b1v[tau][r] = b1[tau * 16 + q * 4 + r];
            b2v[tau][r] = b2[tau * 16 + q * 4 + r];
        }
    }

    const f4 z4 = {0.f, 0.f, 0.f, 0.f};
    short8 h2f[4];

    __syncthreads();

    for (int g = 0; g < 4; ++g) {
        // ef B-fragment: only q==0 lanes carry data (5 real dims + 3 zero pads)
        U8 ef;
        if (q == 0) ef.u = *(const u4*)(efp + (size_t)(ebase + g * 16 + e) * 8);
        else { u4 zz = {0u, 0u, 0u, 0u}; ef.u = zz; }

        f4 c0 = MFMA_B16(w1f[0].v, ef.v, z4);
        f4 c1 = MFMA_B16(w1f[1].v, ef.v, z4);
        us4 pk;
        for (int r = 0; r < 4; ++r) pk[r] = f2bs(fmaxf(c0[r] + b1v[0][r], 0.f));
        *(us4*)&s_h[wave][e * 40 + q * 4] = pk;
        for (int r = 0; r < 4; ++r) pk[r] = f2bs(fmaxf(c1[r] + b1v[1][r], 0.f));
        *(us4*)&s_h[wave][e * 40 + 16 + q * 4] = pk;
        __syncthreads();
        short8 h1f = *(const short8*)&s_h[wave][e * 40 + q * 8];
        c0 = MFMA_B16(w2f[0].v, h1f, z4);
        c1 = MFMA_B16(w2f[1].v, h1f, z4);
        __syncthreads();
        for (int r = 0; r < 4; ++r) pk[r] = f2bs(fmaxf(c0[r] + b2v[0][r], 0.f));
        *(us4*)&s_h[wave][e * 40 + q * 4] = pk;
        for (int r = 0; r < 4; ++r) pk[r] = f2bs(fmaxf(c1[r] + b2v[1][r], 0.f));
        *(us4*)&s_h[wave][e * 40 + 16 + q * 4] = pk;
        __syncthreads();
        h2f[g] = *(const short8*)&s_h[wave][e * 40 + q * 8];
        __syncthreads();
    }

    // main loop: for each h, D = W3^T-frag * h2-frag + b3 (C-init),
    // then msg += x[src][h] * relu(D)
    f4 macc[4][2];
    for (int g = 0; g < 4; ++g) { macc[g][0] = z4; macc[g][1] = z4; }

    for (int h = 0; h < 32; ++h) {
        short8 a0 = *(const short8*)(w3r + h * 1024 + lane * 8);
        short8 a1 = *(const short8*)(w3r + h * 1024 + 512 + lane * 8);
        f4 ci0 = *(const f4*)&s_b3[h * 32 + q * 4];
        f4 ci1 = *(const f4*)&s_b3[h * 32 + 16 + q * 4];
        for (int g = 0; g < 4; ++g) {
            f4 d0 = MFMA_B16(a0, h2f[g], ci0);
            f4 d1 = MFMA_B16(a1, h2f[g], ci1);
            float xv = s_x[wave][g][e * 36 + h];
            for (int r = 0; r < 4; ++r) {
                macc[g][0][r] += xv * fmaxf(d0[r], 0.f);
                macc[g][1][r] += xv * fmaxf(d1[r], 0.f);
            }
        }
    }

    if (STORE) {
        // bf16 store at CSR rank: msg[rank(e)][k], k = p*16 + q*4 + r
        for (int g = 0; g < 4; ++g) {
            int rk = rank[ebase + g * 16 + e];
            unsigned short* mp = msg + (size_t)rk * 32 + q * 4;
            for (int p = 0; p < 2; ++p) {
                us4 pk;
                for (int r = 0; r < 4; ++r) pk[r] = f2bs(macc[g][p][r]);
                *(us4*)(mp + p * 16) = pk;
            }
        }
    } else {
        for (int g = 0; g < 4; ++g) {
            int dste = eidx[E_ + ebase + g * 16 + e];
            float* ap = agg + dste * 32 + q * 4;
            for (int p = 0; p < 2; ++p)
                for (int r = 0; r < 4; ++r)
                    atomicAdd(ap + p * 16 + r, macc[g][p][r]);
        }
    }
}

// ---------------- gather: x += relu(segment_sum(msg) + conv_b), msg in CSR order ----------------
__global__ __launch_bounds__(256) void k_gather(const unsigned short* __restrict__ msg,
                                                const int* __restrict__ off,
                                                const float* __restrict__ cb,
                                                float* __restrict__ x) {
    int tid = blockIdx.x * 256 + threadIdx.x;  // N_*32 exact
    int n = tid >> 5, c = tid & 31;
    int j0 = off[n], j1 = off[n + 1];
    float a = cb[c];
    for (int j = j0; j < j1; ++j)
        a += bs2f(msg[(size_t)j * 32 + c]);
    x[tid] += fmaxf(a, 0.f);
}

// ---------------- node update (fallback path) ----------------
__global__ __launch_bounds__(256) void k_node(float* __restrict__ x, float* __restrict__ agg,
                                              const float* __restrict__ cb) {
    int tid = blockIdx.x * 256 + threadIdx.x;
    int c = tid & 31;
    float a = agg[tid] + cb[c];
    x[tid] += fmaxf(a, 0.f);
    agg[tid] = 0.f;
}

// ---------------- batch pooling: one block per batch, no atomics ----------------
__global__ __launch_bounds__(256) void k_pool2(const float* __restrict__ x,
                                               const int* __restrict__ boff,
                                               const int* __restrict__ bperm,
                                               float* __restrict__ pooled) {
    __shared__ float sp[8][32];
    int b = blockIdx.x, t = threadIdx.x, c = t & 31, slot = t >> 5;
    int j0 = boff[b], j1 = boff[b + 1];
    float a = 0.f;
    for (int j = j0 + slot; j < j1; j += 8)
        a += x[bperm[j] * 32 + c];
    sp[slot][c] = a;
    __syncthreads();
    if (t < 32) {
        float s = 0.f;
        for (int k = 0; k < 8; ++k) s += sp[k][t];
        pooled[b * 32 + t] = s;
    }
}

// ---------------- batch pooling (fallback, atomic) ----------------
__global__ __launch_bounds__(256) void k_pool(const float* __restrict__ x, const int* __restrict__ batch,
                                              float* __restrict__ pooled, int* __restrict__ cnt) {
    int tid = blockIdx.x * 256 + threadIdx.x;
    int n = tid >> 5, c = tid & 31;
    int b = batch[n];
    atomicAdd(&pooled[b * 32 + c], x[tid]);
    if (c == 0) atomicAdd(&cnt[b], 1);
}

// ---------------- head MLP + IDX gather ----------------
__device__ __forceinline__ float selu_(float v) {
    return 1.0507009873554805f * (v > 0.f ? v : 1.6732632423543772f * (expf(v) - 1.f));
}

__global__ __launch_bounds__(128) void k_head(const float* __restrict__ pooled, const int* __restrict__ cnt,
                                              const float* __restrict__ W1, const float* __restrict__ b1,
                                              const float* __restrict__ W2, const float* __restrict__ b2,
                                              const float* __restrict__ W3, const float* __restrict__ b3,
                                              const float* __restrict__ W4, const float* __restrict__ b4,
                                              float* __restrict__ out) {
    __shared__ float s0[32], s1[128], s2[64], s3[32], s4[21];
    int b = blockIdx.x, t = threadIdx.x;
    if (t < 32) s0[t] = pooled[b * 32 + t] / fmaxf((float)cnt[b], 1.f);
    __syncthreads();
    {
        float a = b1[t];
        for (int c = 0; c < 32; ++c) a += s0[c] * W1[c * 128 + t];
        s1[t] = selu_(a);
    }
    __syncthreads();
    if (t < 64) {
        float a = b2[t];
        for (int c = 0; c < 128; ++c) a += s1[c] * W2[c * 64 + t];
        s2[t] = selu_(a);
    }
    __syncthreads();
    if (t < 32) {
        float a = b3[t];
        for (int c = 0; c < 64; ++c) a += s2[c] * W3[c * 32 + t];
        s3[t] = selu_(a);
    }
    __syncthreads();
    if (t < 21) {
        float a = b4[t];
        for (int c = 0; c < 32; ++c) a += s3[c] * W4[c * 21 + t];
        s4[t] = a;
    }
    __syncthreads();
    if (t < 36) out[b * 36 + t] = s4[c_IDX[t]];
}

extern "C" void kernel_launch(void* const* d_in, const int* in_sizes, int n_in,
                              void* d_out, int out_size, void* d_ws, size_t ws_size,
                              hipStream_t stream) {
    const float* na     = (const float*)d_in[0];
    const float* pos    = (const float*)d_in[1];
    const float* shifts = (const float*)d_in[2];
    const float* eattr  = (const float*)d_in[3];
    const int*   eidx   = (const int*)d_in[4];
    const int*   batch  = (const int*)d_in[5];
    const float* embW   = (const float*)d_in[6];
    const float* embB   = (const float*)d_in[7];
    const float* eW1    = (const float*)d_in[8];
    const float* eb1    = (const float*)d_in[9];
    const float* eW2    = (const float*)d_in[10];
    const float* eb2    = (const float*)d_in[11];
    const float* eW3    = (const float*)d_in[12];
    const float* eb3    = (const float*)d_in[13];
    const float* cvb    = (const float*)d_in[14];
    const float* hW1    = (const float*)d_in[15];
    const float* hb1    = (const float*)d_in[16];
    const float* hW2    = (const float*)d_in[17];
    const float* hb2    = (const float*)d_in[18];
    const float* hW3    = (const float*)d_in[19];
    const float* hb3    = (const float*)d_in[20];
    const float* hW4    = (const float*)d_in[21];
    const float* hb4    = (const float*)d_in[22];

    const size_t need_csr = (size_t)(640000 + 2048 + 20000 + 64 + 20004 + 20000 + 320000
                                     + 68 + 64 + 20000) * 4
                          + ((size_t)E_ * 8 + 98304 + (size_t)E_ * 32) * 2;

    if (ws_size >= need_csr) {
        // ---------- CSR path: no hot-loop atomics anywhere ----------
        char* ws = (char*)d_ws;
        float* x      = (float*)ws;                      // 640000 f32
        float* pooled = x + 640000;                      // 2048 f32
        int*   deg    = (int*)(pooled + 2048);           // 20000  \ zeroed together
        int*   bcnt   = deg + 20000;                     // 64     /
        int*   off    = bcnt + 64;                       // 20001 (pad 20004)
        int*   cur    = off + 20004;                     // 20000
        int*   rank   = cur + 20000;                     // 320000
        int*   boff   = rank + 320000;                   // 65 (pad 68)
        int*   bcur   = boff + 68;                       // 64
        int*   bperm  = bcur + 64;                       // 20000
        unsigned short* efp = (unsigned short*)(bperm + 20000);  // E_*8 bf16
        unsigned short* w3r = efp + (size_t)E_ * 8;              // 98304 bf16
        unsigned short* msg = w3r + 98304;                       // E_*32 bf16

        k_init_x<<<2500, 256, 0, stream>>>(na, embW, embB, x, deg, 20064);  // zeros deg+bcnt
        k_edge_prep<<<1250, 256, 0, stream>>>(pos, shifts, eattr, eidx, efp);
        k_repack<<<48, 256, 0, stream>>>(eW3, w3r);
        k_hist<<<1250, 256, 0, stream>>>(eidx, deg);
        k_bhist<<<79, 256, 0, stream>>>(batch, bcnt);
        k_scan<<<1, 1024, 0, stream>>>(deg, off, cur);
        k_bscan<<<1, 64, 0, stream>>>(bcnt, boff, bcur);
        k_fill<<<1250, 256, 0, stream>>>(eidx, cur, rank);
        k_bfill<<<79, 256, 0, stream>>>(batch, bcur, bperm);

        for (int i = 0; i < 3; ++i) {
            k_edge<true><<<1250, 256, 0, stream>>>(efp, eidx, rank, x, nullptr, msg,
                                                   eW1 + i * 160, eb1 + i * 32,
                                                   eW2 + i * 1024, eb2 + i * 32,
                                                   w3r + i * 32768, eb3 + i * 1024);
            k_gather<<<2500, 256, 0, stream>>>(msg, off, cvb + i * 32, x);
        }

        k_pool2<<<64, 256, 0, stream>>>(x, boff, bperm, pooled);
        k_head<<<64, 128, 0, stream>>>(pooled, bcnt, hW1, hb1, hW2, hb2, hW3, hb3, hW4, hb4,
                                       (float*)d_out);
    } else {
        // ---------- fallback: atomic scatter path ----------
        char* ws = (char*)d_ws;
        float* x      = (float*)ws;                   // 640000 f32
        float* agg    = x + 640000;                   // 640000 f32
        float* pooled = agg + 640000;                 // 2048 f32
        int*   cnt    = (int*)(pooled + 2048);        // 64 i32
        unsigned short* efp = (unsigned short*)(cnt + 64);   // E_*8 bf16
        unsigned short* w3r = efp + (size_t)E_ * 8;          // 98304 bf16

        k_init_x<<<2500, 256, 0, stream>>>(na, embW, embB, x, nullptr, 0);
        hipMemsetAsync(agg, 0, 640000 * sizeof(float), stream);
        k_edge_prep<<<1250, 256, 0, stream>>>(pos, shifts, eattr, eidx, efp);
        k_repack<<<48, 256, 0, stream>>>(eW3, w3r);
        k_zero_pool<<<9, 256, 0, stream>>>(pooled, cnt);

        for (int i = 0; i < 3; ++i) {
            k_edge<false><<<1250, 256, 0, stream>>>(efp, eidx, nullptr, x, agg, nullptr,
                                                    eW1 + i * 160, eb1 + i * 32,
                                                    eW2 + i * 1024, eb2 + i * 32,
                                                    w3r + i * 32768, eb3 + i * 1024);
            k_node<<<2500, 256, 0, stream>>>(x, agg, cvb + i * 32);
        }

        k_pool<<<2500, 256, 0, stream>>>(x, batch, pooled, cnt);
        k_head<<<64, 128, 0, stream>>>(pooled, cnt, hW1, hb1, hW2, hb2, hW3, hb3, hW4, hb4,
                                       (float*)d_out);
    }
}

// Round 5
// 453.024 us; speedup vs baseline: 1.4598x; 1.0970x over previous
//
#include <hip/hip_runtime.h>
#include <hip/hip_bf16.h>

#define N_ 20000
#define E_ 320000
#define B_ 64

typedef __attribute__((ext_vector_type(8))) short short8;
typedef __attribute__((ext_vector_type(4))) float f4;
typedef __attribute__((ext_vector_type(4))) unsigned int u4;
typedef __attribute__((ext_vector_type(4))) unsigned short us4;

union U8 { short s[8]; unsigned short us[8]; short8 v; u4 u; };

__device__ __forceinline__ float bs2f(unsigned short s) {
    return __uint_as_float(((unsigned int)s) << 16);
}
__device__ __forceinline__ unsigned short f2bs(float f) {
    unsigned int u = __float_as_uint(f);
    unsigned int r = u + 0x7FFFu + ((u >> 16) & 1u);  // round-to-nearest-even
    return (unsigned short)(r >> 16);
}

// wave-local LDS drain: s_h/s_x are per-wave buffers, no block barrier needed
#define WAVE_LDS_WAIT() asm volatile("s_waitcnt lgkmcnt(0)" ::: "memory")

#define MFMA_B16(a, b, c) __builtin_amdgcn_mfma_f32_16x16x32_bf16(a, b, c, 0, 0, 0)

__device__ __constant__ int c_IDX[36] = {
    0,1,2,3,4,5, 1,6,7,8,9,10, 2,7,11,12,13,14,
    3,8,12,15,16,17, 4,9,13,16,18,19, 5,10,14,17,19,20};

// ================= fused setup: init x/xb + zero deg/bcnt | edge_prep | repack =================
__global__ __launch_bounds__(256) void k_setup(
    const float* __restrict__ na, const float* __restrict__ eW, const float* __restrict__ eb,
    float* __restrict__ x, unsigned short* __restrict__ xb, int* __restrict__ deg /*deg+bcnt contiguous*/,
    const float* __restrict__ pos, const float* __restrict__ shifts, const float* __restrict__ eattr,
    const int* __restrict__ eidx, unsigned short* __restrict__ efp,
    const float* __restrict__ w3, unsigned short* __restrict__ w3r) {
    int bid = blockIdx.x, t = threadIdx.x;
    if (bid < 2500) {
        int tid = bid * 256 + t;  // < 640000 exact
        int n = tid >> 5, c = tid & 31;
        float v = na[n] * eW[c] + eb[c];
        x[tid] = v;
        xb[tid] = f2bs(v);
        if (tid < 20064) deg[tid] = 0;  // zero deg[20000] + bcnt[64]
    } else if (bid < 3750) {
        int e = (bid - 2500) * 256 + t;  // < E_ exact
        int s = eidx[e], d = eidx[E_ + e];
        float vx = pos[d * 3 + 0] - pos[s * 3 + 0] + shifts[e * 3 + 0];
        float vy = pos[d * 3 + 1] - pos[s * 3 + 1] + shifts[e * 3 + 1];
        float vz = pos[d * 3 + 2] - pos[s * 3 + 2] + shifts[e * 3 + 2];
        float ln = sqrtf(vx * vx + vy * vy + vz * vz);
        U8 o;
        o.us[0] = f2bs(vx); o.us[1] = f2bs(vy); o.us[2] = f2bs(vz);
        o.us[3] = f2bs(ln); o.us[4] = f2bs(eattr[e]);
        o.us[5] = 0; o.us[6] = 0; o.us[7] = 0;
        *(u4*)(efp + (size_t)e * 8) = o.u;
    } else {
        int tid = (bid - 3750) * 256 + t;  // < 12288 exact
        int l = tid & 63, t2 = (tid >> 6) & 63, i = tid >> 12;
        int q = l >> 4, m = l & 15;
        U8 o;
        for (int j = 0; j < 8; ++j) {
            int k = q * 8 + j;
            o.us[j] = f2bs(w3[(i * 32 + k) * 1024 + t2 * 16 + m]);
        }
        *(u4*)(w3r + (size_t)tid * 8) = o.u;
    }
}

// ================= fused histograms =================
__global__ __launch_bounds__(256) void k_hists(const int* __restrict__ eidx, int* __restrict__ deg,
                                               const int* __restrict__ batch, int* __restrict__ bcnt) {
    int bid = blockIdx.x, t = threadIdx.x;
    if (bid < 1250) {
        int e = bid * 256 + t;
        atomicAdd(&deg[eidx[E_ + e]], 1);
    } else {
        __shared__ int s[64];
        if (t < 64) s[t] = 0;
        __syncthreads();
        int n = (bid - 1250) * 256 + t;
        if (n < N_) atomicAdd(&s[batch[n]], 1);
        __syncthreads();
        if (t < 64 && s[t]) atomicAdd(&bcnt[t], s[t]);
    }
}

// ================= fused scans (block 0: node CSR, block 1: batch CSR) =================
__global__ __launch_bounds__(1024) void k_scans(const int* __restrict__ deg,
                                                int* __restrict__ off, int* __restrict__ cur,
                                                const int* __restrict__ bcnt,
                                                int* __restrict__ boff, int* __restrict__ bcur) {
    int t = threadIdx.x;
    if (blockIdx.x == 0) {
        __shared__ int sh[1024];
        int base = t * 20;  // 1024*20 >= N_
        int loc[20]; int s = 0;
        for (int k = 0; k < 20; ++k) {
            int i = base + k;
            int v = (i < N_) ? deg[i] : 0;
            loc[k] = s; s += v;
        }
        sh[t] = s;
        __syncthreads();
        for (int d = 1; d < 1024; d <<= 1) {
            int val = (t >= d) ? sh[t - d] : 0;
            __syncthreads();
            sh[t] += val;
            __syncthreads();
        }
        int excl = sh[t] - s;
        for (int k = 0; k < 20; ++k) {
            int i = base + k;
            if (i < N_) { int o = excl + loc[k]; off[i] = o; cur[i] = o; }
        }
        if (t == 1023) off[N_] = sh[1023];
    } else {
        __shared__ int sh[64];
        int v = 0;
        if (t < 64) { v = bcnt[t]; sh[t] = v; }
        __syncthreads();
        for (int d = 1; d < 64; d <<= 1) {
            int val = (t >= d && t < 64) ? sh[t - d] : 0;
            __syncthreads();
            if (t < 64) sh[t] += val;
            __syncthreads();
        }
        if (t < 64) {
            int excl = sh[t] - v;
            boff[t] = excl; bcur[t] = excl;
            if (t == 63) boff[64] = sh[63];
        }
    }
}

// ================= fused fills =================
__global__ __launch_bounds__(256) void k_fills(const int* __restrict__ eidx,
                                               int* __restrict__ cur, int* __restrict__ rank,
                                               const int* __restrict__ batch,
                                               int* __restrict__ bcur, int* __restrict__ bperm) {
    int bid = blockIdx.x, t = threadIdx.x;
    if (bid < 1250) {
        int e = bid * 256 + t;
        rank[e] = atomicAdd(&cur[eidx[E_ + e]], 1);
    } else {
        int n = (bid - 1250) * 256 + t;
        if (n < N_) {
            int p = atomicAdd(&bcur[batch[n]], 1);
            bperm[p] = n;
        }
    }
}

// ================= main edge kernel: one layer, 64 edges/wave, 1 barrier =================
// STORE=true: bf16 msg rows at CSR rank. STORE=false: atomicAdd into fp32 agg (fallback).
template <bool STORE>
__global__ __launch_bounds__(256) void k_edge(
    const unsigned short* __restrict__ efp, const int* __restrict__ eidx,
    const int* __restrict__ rank,
    const unsigned short* __restrict__ xb, float* __restrict__ agg, unsigned short* __restrict__ msg,
    const float* __restrict__ w1, const float* __restrict__ b1,
    const float* __restrict__ w2, const float* __restrict__ b2,
    const unsigned short* __restrict__ w3r, const float* __restrict__ b3) {
    __shared__ float s_b3[1024];                            // 4 KB (block-shared)
    __shared__ __align__(16) unsigned short s_h[4][640];    // per-wave transpose buf, stride 40
    __shared__ __align__(16) unsigned short s_x[4][4][640]; // per-wave bf16 x tiles, stride 40

    const int t = threadIdx.x;
    for (int k = t; k < 1024; k += 256) s_b3[k] = b3[k];

    const int wave = t >> 6, lane = t & 63;
    const int q = lane >> 4, e = lane & 15;
    const int ebase = (blockIdx.x * 4 + wave) * 64;

    // stage xb[src] tiles (bf16, 16B/lane), per-wave LDS only
    for (int g = 0; g < 4; ++g) {
        int srce = eidx[ebase + g * 16 + e];
        u4 xv16 = *(const u4*)(xb + srce * 32 + q * 8);
        *(u4*)&s_x[wave][g][e * 40 + q * 8] = xv16;
    }

    // loop-invariant W1^T / W2^T fragments (bf16) + bias regs (fp32)
    U8 w1f[2], w2f[2];
    float b1v[2][4], b2v[2][4];
    for (int tau = 0; tau < 2; ++tau) {
        for (int j = 0; j < 8; ++j) {
            int k = q * 8 + j;
            w1f[tau].us[j] = (k < 5) ? f2bs(w1[k * 32 + tau * 16 + e]) : (unsigned short)0;
            w2f[tau].us[j] = f2bs(w2[k * 32 + tau * 16 + e]);
        }
        for (int r = 0; r < 4; ++r) {
            b1v[tau][r] = b1[tau * 16 + q * 4 + r];
            b2v[tau][r] = b2[tau * 16 + q * 4 + r];
        }
    }

    const f4 z4 = {0.f, 0.f, 0.f, 0.f};
    short8 h2f[4];

    // per-g MLP: all LDS traffic here is within-wave -> wave-local waits, no barrier
    for (int g = 0; g < 4; ++g) {
        U8 ef;
        if (q == 0) ef.u = *(const u4*)(efp + (size_t)(ebase + g * 16 + e) * 8);
        else { u4 zz = {0u, 0u, 0u, 0u}; ef.u = zz; }

        f4 c0 = MFMA_B16(w1f[0].v, ef.v, z4);
        f4 c1 = MFMA_B16(w1f[1].v, ef.v, z4);
        us4 pk;
        for (int r = 0; r < 4; ++r) pk[r] = f2bs(fmaxf(c0[r] + b1v[0][r], 0.f));
        *(us4*)&s_h[wave][e * 40 + q * 4] = pk;
        for (int r = 0; r < 4; ++r) pk[r] = f2bs(fmaxf(c1[r] + b1v[1][r], 0.f));
        *(us4*)&s_h[wave][e * 40 + 16 + q * 4] = pk;
        WAVE_LDS_WAIT();
        short8 h1f = *(const short8*)&s_h[wave][e * 40 + q * 8];
        c0 = MFMA_B16(w2f[0].v, h1f, z4);   // use of h1f forces lgkm wait
        c1 = MFMA_B16(w2f[1].v, h1f, z4);
        for (int r = 0; r < 4; ++r) pk[r] = f2bs(fmaxf(c0[r] + b2v[0][r], 0.f));
        *(us4*)&s_h[wave][e * 40 + q * 4] = pk;
        for (int r = 0; r < 4; ++r) pk[r] = f2bs(fmaxf(c1[r] + b2v[1][r], 0.f));
        *(us4*)&s_h[wave][e * 40 + 16 + q * 4] = pk;
        WAVE_LDS_WAIT();
        h2f[g] = *(const short8*)&s_h[wave][e * 40 + q * 8];
        WAVE_LDS_WAIT();  // drain read before next g overwrites s_h
    }

    __syncthreads();  // single barrier: s_b3 visibility across waves

    // main loop: D = W3^T-frag * h2-frag + b3 (C-init), then msg += x[src][h] * relu(D)
    f4 macc[4][2];
    for (int g = 0; g < 4; ++g) { macc[g][0] = z4; macc[g][1] = z4; }

#pragma unroll 2
    for (int h = 0; h < 32; ++h) {
        short8 a0 = *(const short8*)(w3r + h * 1024 + lane * 8);
        short8 a1 = *(const short8*)(w3r + h * 1024 + 512 + lane * 8);
        f4 ci0 = *(const f4*)&s_b3[h * 32 + q * 4];
        f4 ci1 = *(const f4*)&s_b3[h * 32 + 16 + q * 4];
        for (int g = 0; g < 4; ++g) {
            f4 d0 = MFMA_B16(a0, h2f[g], ci0);
            f4 d1 = MFMA_B16(a1, h2f[g], ci1);
            float xv = bs2f(s_x[wave][g][e * 40 + h]);
            for (int r = 0; r < 4; ++r) {
                macc[g][0][r] += xv * fmaxf(d0[r], 0.f);
                macc[g][1][r] += xv * fmaxf(d1[r], 0.f);
            }
        }
    }

    if (STORE) {
        for (int g = 0; g < 4; ++g) {
            int rk = rank[ebase + g * 16 + e];
            unsigned short* mp = msg + (size_t)rk * 32 + q * 4;
            for (int p = 0; p < 2; ++p) {
                us4 pk;
                for (int r = 0; r < 4; ++r) pk[r] = f2bs(macc[g][p][r]);
                *(us4*)(mp + p * 16) = pk;
            }
        }
    } else {
        for (int g = 0; g < 4; ++g) {
            int dste = eidx[E_ + ebase + g * 16 + e];
            float* ap = agg + dste * 32 + q * 4;
            for (int p = 0; p < 2; ++p)
                for (int r = 0; r < 4; ++r)
                    atomicAdd(ap + p * 16 + r, macc[g][p][r]);
        }
    }
}

// ================= gather: x += relu(segment_sum(msg) + conv_b); maintain bf16 mirror =================
__global__ __launch_bounds__(256) void k_gather(const unsigned short* __restrict__ msg,
                                                const int* __restrict__ off,
                                                const float* __restrict__ cb,
                                                float* __restrict__ x,
                                                unsigned short* __restrict__ xb) {
    int tid = blockIdx.x * 256 + threadIdx.x;  // N_*32 exact
    int n = tid >> 5, c = tid & 31;
    int j0 = off[n], j1 = off[n + 1];
    float a = cb[c];
    for (int j = j0; j < j1; ++j)
        a += bs2f(msg[(size_t)j * 32 + c]);
    float v = x[tid] + fmaxf(a, 0.f);
    x[tid] = v;
    xb[tid] = f2bs(v);
}

// ================= node update (fallback) =================
__global__ __launch_bounds__(256) void k_node(float* __restrict__ x, unsigned short* __restrict__ xb,
                                              float* __restrict__ agg, const float* __restrict__ cb) {
    int tid = blockIdx.x * 256 + threadIdx.x;
    int c = tid & 31;
    float a = agg[tid] + cb[c];
    float v = x[tid] + fmaxf(a, 0.f);
    x[tid] = v;
    xb[tid] = f2bs(v);
    agg[tid] = 0.f;
}

__device__ __forceinline__ float selu_(float v) {
    return 1.0507009873554805f * (v > 0.f ? v : 1.6732632423543772f * (expf(v) - 1.f));
}

// ================= fused pooling + head MLP + IDX gather (one block per batch) =================
__global__ __launch_bounds__(256) void k_pool_head(const float* __restrict__ x,
                                                   const int* __restrict__ boff,
                                                   const int* __restrict__ bperm,
                                                   const float* __restrict__ W1, const float* __restrict__ b1,
                                                   const float* __restrict__ W2, const float* __restrict__ b2,
                                                   const float* __restrict__ W3, const float* __restrict__ b3,
                                                   const float* __restrict__ W4, const float* __restrict__ b4,
                                                   float* __restrict__ out) {
    __shared__ float sp[8][32];
    __shared__ float s0[32], s1[128], s2[64], s3[32], s4[21];
    int b = blockIdx.x, t = threadIdx.x, c = t & 31, slot = t >> 5;
    int j0 = boff[b], j1 = boff[b + 1];
    float a = 0.f;
    for (int j = j0 + slot; j < j1; j += 8)
        a += x[bperm[j] * 32 + c];
    sp[slot][c] = a;
    __syncthreads();
    if (t < 32) {
        float s = 0.f;
        for (int k = 0; k < 8; ++k) s += sp[k][t];
        s0[t] = s / fmaxf((float)(j1 - j0), 1.f);
    }
    __syncthreads();
    if (t < 128) {
        float v = b1[t];
        for (int cc = 0; cc < 32; ++cc) v += s0[cc] * W1[cc * 128 + t];
        s1[t] = selu_(v);
    }
    __syncthreads();
    if (t < 64) {
        float v = b2[t];
        for (int cc = 0; cc < 128; ++cc) v += s1[cc] * W2[cc * 64 + t];
        s2[t] = selu_(v);
    }
    __syncthreads();
    if (t < 32) {
        float v = b3[t];
        for (int cc = 0; cc < 64; ++cc) v += s2[cc] * W3[cc * 32 + t];
        s3[t] = selu_(v);
    }
    __syncthreads();
    if (t < 21) {
        float v = b4[t];
        for (int cc = 0; cc < 32; ++cc) v += s3[cc] * W4[cc * 21 + t];
        s4[t] = v;
    }
    __syncthreads();
    if (t < 36) out[b * 36 + t] = s4[c_IDX[t]];
}

// ================= fallback helpers =================
__global__ __launch_bounds__(256) void k_init_fb(const float* __restrict__ na,
                                                 const float* __restrict__ eW,
                                                 const float* __restrict__ eb,
                                                 float* __restrict__ x, unsigned short* __restrict__ xb) {
    int tid = blockIdx.x * 256 + threadIdx.x;
    int n = tid >> 5, c = tid & 31;
    float v = na[n] * eW[c] + eb[c];
    x[tid] = v;
    xb[tid] = f2bs(v);
}

__global__ __launch_bounds__(256) void k_zero_pool(float* __restrict__ pooled, int* __restrict__ cnt) {
    int tid = blockIdx.x * 256 + threadIdx.x;
    if (tid < 2048) pooled[tid] = 0.f;
    else if (tid < 2112) cnt[tid - 2048] = 0;
}

__global__ __launch_bounds__(256) void k_pool(const float* __restrict__ x, const int* __restrict__ batch,
                                              float* __restrict__ pooled, int* __restrict__ cnt) {
    int tid = blockIdx.x * 256 + threadIdx.x;
    int n = tid >> 5, c = tid & 31;
    int b = batch[n];
    atomicAdd(&pooled[b * 32 + c], x[tid]);
    if (c == 0) atomicAdd(&cnt[b], 1);
}

__global__ __launch_bounds__(128) void k_head(const float* __restrict__ pooled, const int* __restrict__ cnt,
                                              const float* __restrict__ W1, const float* __restrict__ b1,
                                              const float* __restrict__ W2, const float* __restrict__ b2,
                                              const float* __restrict__ W3, const float* __restrict__ b3,
                                              const float* __restrict__ W4, const float* __restrict__ b4,
                                              float* __restrict__ out) {
    __shared__ float s0[32], s1[128], s2[64], s3[32], s4[21];
    int b = blockIdx.x, t = threadIdx.x;
    if (t < 32) s0[t] = pooled[b * 32 + t] / fmaxf((float)cnt[b], 1.f);
    __syncthreads();
    {
        float a = b1[t];
        for (int c = 0; c < 32; ++c) a += s0[c] * W1[c * 128 + t];
        s1[t] = selu_(a);
    }
    __syncthreads();
    if (t < 64) {
        float a = b2[t];
        for (int c = 0; c < 128; ++c) a += s1[c] * W2[c * 64 + t];
        s2[t] = selu_(a);
    }
    __syncthreads();
    if (t < 32) {
        float a = b3[t];
        for (int c = 0; c < 64; ++c) a += s2[c] * W3[c * 32 + t];
        s3[t] = selu_(a);
    }
    __syncthreads();
    if (t < 21) {
        float a = b4[t];
        for (int c = 0; c < 32; ++c) a += s3[c] * W4[c * 21 + t];
        s4[t] = a;
    }
    __syncthreads();
    if (t < 36) out[b * 36 + t] = s4[c_IDX[t]];
}

__global__ __launch_bounds__(256) void k_prep_fb(const float* __restrict__ pos,
                                                 const float* __restrict__ shifts,
                                                 const float* __restrict__ eattr,
                                                 const int* __restrict__ eidx,
                                                 unsigned short* __restrict__ efp) {
    int e = blockIdx.x * 256 + threadIdx.x;
    int s = eidx[e], d = eidx[E_ + e];
    float vx = pos[d * 3 + 0] - pos[s * 3 + 0] + shifts[e * 3 + 0];
    float vy = pos[d * 3 + 1] - pos[s * 3 + 1] + shifts[e * 3 + 1];
    float vz = pos[d * 3 + 2] - pos[s * 3 + 2] + shifts[e * 3 + 2];
    float ln = sqrtf(vx * vx + vy * vy + vz * vz);
    U8 o;
    o.us[0] = f2bs(vx); o.us[1] = f2bs(vy); o.us[2] = f2bs(vz);
    o.us[3] = f2bs(ln); o.us[4] = f2bs(eattr[e]);
    o.us[5] = 0; o.us[6] = 0; o.us[7] = 0;
    *(u4*)(efp + (size_t)e * 8) = o.u;
}

__global__ __launch_bounds__(256) void k_repack_fb(const float* __restrict__ w3,
                                                   unsigned short* __restrict__ w3r) {
    int tid = blockIdx.x * 256 + threadIdx.x;
    int l = tid & 63, t2 = (tid >> 6) & 63, i = tid >> 12;
    int q = l >> 4, m = l & 15;
    U8 o;
    for (int j = 0; j < 8; ++j) {
        int k = q * 8 + j;
        o.us[j] = f2bs(w3[(i * 32 + k) * 1024 + t2 * 16 + m]);
    }
    *(u4*)(w3r + (size_t)tid * 8) = o.u;
}

extern "C" void kernel_launch(void* const* d_in, const int* in_sizes, int n_in,
                              void* d_out, int out_size, void* d_ws, size_t ws_size,
                              hipStream_t stream) {
    const float* na     = (const float*)d_in[0];
    const float* pos    = (const float*)d_in[1];
    const float* shifts = (const float*)d_in[2];
    const float* eattr  = (const float*)d_in[3];
    const int*   eidx   = (const int*)d_in[4];
    const int*   batch  = (const int*)d_in[5];
    const float* embW   = (const float*)d_in[6];
    const float* embB   = (const float*)d_in[7];
    const float* eW1    = (const float*)d_in[8];
    const float* eb1    = (const float*)d_in[9];
    const float* eW2    = (const float*)d_in[10];
    const float* eb2    = (const float*)d_in[11];
    const float* eW3    = (const float*)d_in[12];
    const float* eb3    = (const float*)d_in[13];
    const float* cvb    = (const float*)d_in[14];
    const float* hW1    = (const float*)d_in[15];
    const float* hb1    = (const float*)d_in[16];
    const float* hW2    = (const float*)d_in[17];
    const float* hb2    = (const float*)d_in[18];
    const float* hW3    = (const float*)d_in[19];
    const float* hb3    = (const float*)d_in[20];
    const float* hW4    = (const float*)d_in[21];
    const float* hb4    = (const float*)d_in[22];

    // CSR layout: x | xb | deg | bcnt | off | cur | rank | boff | bcur | bperm | efp | w3r | msg
    const size_t need_csr = (size_t)640000 * 4 + (size_t)640000 * 2
                          + (size_t)(20000 + 64 + 20004 + 20000 + 320000 + 68 + 64 + 20000) * 4
                          + ((size_t)E_ * 8 + 98304 + (size_t)E_ * 32) * 2;

    if (ws_size >= need_csr) {
        char* ws = (char*)d_ws;
        float* x            = (float*)ws;                        // 640000 f32
        unsigned short* xb  = (unsigned short*)(x + 640000);     // 640000 bf16
        int*   deg    = (int*)(xb + 640000);                     // 20000
        int*   bcnt   = deg + 20000;                             // 64 (contiguous with deg)
        int*   off    = bcnt + 64;                               // 20001 (pad 20004)
        int*   cur    = off + 20004;                             // 20000
        int*   rank   = cur + 20000;                             // 320000
        int*   boff   = rank + 320000;                           // 65 (pad 68)
        int*   bcur   = boff + 68;                               // 64
        int*   bperm  = bcur + 64;                               // 20000
        unsigned short* efp = (unsigned short*)(bperm + 20000);  // E_*8 bf16
        unsigned short* w3r = efp + (size_t)E_ * 8;              // 98304 bf16
        unsigned short* msg = w3r + 98304;                       // E_*32 bf16

        k_setup<<<3798, 256, 0, stream>>>(na, embW, embB, x, xb, deg,
                                          pos, shifts, eattr, eidx, efp, eW3, w3r);
        k_hists<<<1329, 256, 0, stream>>>(eidx, deg, batch, bcnt);
        k_scans<<<2, 1024, 0, stream>>>(deg, off, cur, bcnt, boff, bcur);
        k_fills<<<1329, 256, 0, stream>>>(eidx, cur, rank, batch, bcur, bperm);

        for (int i = 0; i < 3; ++i) {
            k_edge<true><<<1250, 256, 0, stream>>>(efp, eidx, rank, xb, nullptr, msg,
                                                   eW1 + i * 160, eb1 + i * 32,
                                                   eW2 + i * 1024, eb2 + i * 32,
                                                   w3r + i * 32768, eb3 + i * 1024);
            k_gather<<<2500, 256, 0, stream>>>(msg, off, cvb + i * 32, x, xb);
        }

        k_pool_head<<<64, 256, 0, stream>>>(x, boff, bperm,
                                            hW1, hb1, hW2, hb2, hW3, hb3, hW4, hb4,
                                            (float*)d_out);
    } else {
        // fallback: atomic scatter path
        char* ws = (char*)d_ws;
        float* x           = (float*)ws;                      // 640000 f32
        unsigned short* xb = (unsigned short*)(x + 640000);   // 640000 bf16
        float* agg    = (float*)(xb + 640000);                // 640000 f32
        float* pooled = agg + 640000;                         // 2048 f32
        int*   cnt    = (int*)(pooled + 2048);                // 64
        unsigned short* efp = (unsigned short*)(cnt + 64);    // E_*8 bf16
        unsigned short* w3r = efp + (size_t)E_ * 8;           // 98304 bf16

        k_init_fb<<<2500, 256, 0, stream>>>(na, embW, embB, x, xb);
        hipMemsetAsync(agg, 0, 640000 * sizeof(float), stream);
        k_prep_fb<<<1250, 256, 0, stream>>>(pos, shifts, eattr, eidx, efp);
        k_repack_fb<<<48, 256, 0, stream>>>(eW3, w3r);
        k_zero_pool<<<9, 256, 0, stream>>>(pooled, cnt);

        for (int i = 0; i < 3; ++i) {
            k_edge<false><<<1250, 256, 0, stream>>>(efp, eidx, nullptr, xb, agg, nullptr,
                                                    eW1 + i * 160, eb1 + i * 32,
                                                    eW2 + i * 1024, eb2 + i * 32,
                                                    w3r + i * 32768, eb3 + i * 1024);
            k_node<<<2500, 256, 0, stream>>>(x, xb, agg, cvb + i * 32);
        }

        k_pool<<<2500, 256, 0, stream>>>(x, batch, pooled, cnt);
        k_head<<<64, 128, 0, stream>>>(pooled, cnt, hW1, hb1, hW2, hb2, hW3, hb3, hW4, hb4,
                                       (float*)d_out);
    }
}

// Round 7
// 451.562 us; speedup vs baseline: 1.4646x; 1.0032x over previous
//
#include <hip/hip_runtime.h>
#include <hip/hip_bf16.h>

#define N_ 20000
#define E_ 320000
#define B_ 64

typedef __attribute__((ext_vector_type(8))) short short8;
typedef __attribute__((ext_vector_type(4))) float f4;
typedef __attribute__((ext_vector_type(2))) float f2v;
typedef __attribute__((ext_vector_type(4))) unsigned int u4;
typedef __attribute__((ext_vector_type(4))) unsigned short us4;

union U8 { short s[8]; unsigned short us[8]; short8 v; u4 u; };
union F4 { f4 v; f2v h[2]; float f[4]; };

__device__ __forceinline__ float bs2f(unsigned short s) {
    return __uint_as_float(((unsigned int)s) << 16);
}
__device__ __forceinline__ unsigned short f2bs(float f) {
    unsigned int u = __float_as_uint(f);
    unsigned int r = u + 0x7FFFu + ((u >> 16) & 1u);  // round-to-nearest-even
    return (unsigned short)(r >> 16);
}

// wave-local LDS drain: s_h is a per-wave buffer, no block barrier needed
#define WAVE_LDS_WAIT() asm volatile("s_waitcnt lgkmcnt(0)" ::: "memory")

#define MFMA_B16(a, b, c) __builtin_amdgcn_mfma_f32_16x16x32_bf16(a, b, c, 0, 0, 0)

__device__ __constant__ int c_IDX[36] = {
    0,1,2,3,4,5, 1,6,7,8,9,10, 2,7,11,12,13,14,
    3,8,12,15,16,17, 4,9,13,16,18,19, 5,10,14,17,19,20};

// ================= fused setup: init x + zero deg/bcnt | edge_prep | repack w3/w1/w2 =================
__global__ __launch_bounds__(256) void k_setup(
    const float* __restrict__ na, const float* __restrict__ eW, const float* __restrict__ eb,
    float* __restrict__ x, int* __restrict__ deg /*deg+bcnt contiguous*/,
    const float* __restrict__ pos, const float* __restrict__ shifts, const float* __restrict__ eattr,
    const int* __restrict__ eidx, unsigned short* __restrict__ efp,
    const float* __restrict__ w3, unsigned short* __restrict__ w3r,
    const float* __restrict__ w1, const float* __restrict__ w2,
    unsigned short* __restrict__ w1r, unsigned short* __restrict__ w2r) {
    int bid = blockIdx.x, t = threadIdx.x;
    if (bid < 2500) {
        int tid = bid * 256 + t;  // < 640000 exact
        int n = tid >> 5, c = tid & 31;
        x[tid] = na[n] * eW[c] + eb[c];
        if (tid < 20064) deg[tid] = 0;  // zero deg[20000] + bcnt[64]
    } else if (bid < 3750) {
        int e = (bid - 2500) * 256 + t;  // < E_ exact
        int s = eidx[e], d = eidx[E_ + e];
        float vx = pos[d * 3 + 0] - pos[s * 3 + 0] + shifts[e * 3 + 0];
        float vy = pos[d * 3 + 1] - pos[s * 3 + 1] + shifts[e * 3 + 1];
        float vz = pos[d * 3 + 2] - pos[s * 3 + 2] + shifts[e * 3 + 2];
        float ln = sqrtf(vx * vx + vy * vy + vz * vz);
        U8 o;
        o.us[0] = f2bs(vx); o.us[1] = f2bs(vy); o.us[2] = f2bs(vz);
        o.us[3] = f2bs(ln); o.us[4] = f2bs(eattr[e]);
        o.us[5] = 0; o.us[6] = 0; o.us[7] = 0;
        *(u4*)(efp + (size_t)e * 8) = o.u;
    } else if (bid < 3798) {
        int tid = (bid - 3750) * 256 + t;  // < 12288 exact
        int l = tid & 63, t2 = (tid >> 6) & 63, i = tid >> 12;
        int q = l >> 4, m = l & 15;
        U8 o;
        for (int j = 0; j < 8; ++j) {
            int k = q * 8 + j;
            o.us[j] = f2bs(w3[(i * 32 + k) * 1024 + t2 * 16 + m]);
        }
        *(u4*)(w3r + (size_t)tid * 8) = o.u;
    } else {
        int tid = (bid - 3798) * 256 + t;  // < 768 used
        if (tid < 768) {
            bool isw2 = tid >= 384;
            int idx = isw2 ? tid - 384 : tid;   // FIX: 384 not pow2; no & mask
            int i = idx >> 7;                   // layer
            int tau = (idx >> 6) & 1;
            int l = idx & 63;
            int q = l >> 4, m = l & 15;
            U8 o;
            for (int j = 0; j < 8; ++j) {
                int k = q * 8 + j;
                if (!isw2) o.us[j] = (k < 5) ? f2bs(w1[i * 160 + k * 32 + tau * 16 + m]) : (unsigned short)0;
                else       o.us[j] = f2bs(w2[i * 1024 + k * 32 + tau * 16 + m]);
            }
            unsigned short* dst = (isw2 ? w2r : w1r) + i * 1024 + tau * 512 + l * 8;
            *(u4*)dst = o.u;
        }
    }
}

// ================= fused histograms =================
__global__ __launch_bounds__(256) void k_hists(const int* __restrict__ eidx, int* __restrict__ deg,
                                               const int* __restrict__ batch, int* __restrict__ bcnt) {
    int bid = blockIdx.x, t = threadIdx.x;
    if (bid < 1250) {
        int e = bid * 256 + t;
        atomicAdd(&deg[eidx[E_ + e]], 1);
    } else {
        __shared__ int s[64];
        if (t < 64) s[t] = 0;
        __syncthreads();
        int n = (bid - 1250) * 256 + t;
        if (n < N_) atomicAdd(&s[batch[n]], 1);
        __syncthreads();
        if (t < 64 && s[t]) atomicAdd(&bcnt[t], s[t]);
    }
}

// ================= fused scans =================
__global__ __launch_bounds__(1024) void k_scans(const int* __restrict__ deg,
                                                int* __restrict__ off, int* __restrict__ cur,
                                                const int* __restrict__ bcnt,
                                                int* __restrict__ boff, int* __restrict__ bcur) {
    int t = threadIdx.x;
    if (blockIdx.x == 0) {
        __shared__ int sh[1024];
        int base = t * 20;
        int loc[20]; int s = 0;
        for (int k = 0; k < 20; ++k) {
            int i = base + k;
            int v = (i < N_) ? deg[i] : 0;
            loc[k] = s; s += v;
        }
        sh[t] = s;
        __syncthreads();
        for (int d = 1; d < 1024; d <<= 1) {
            int val = (t >= d) ? sh[t - d] : 0;
            __syncthreads();
            sh[t] += val;
            __syncthreads();
        }
        int excl = sh[t] - s;
        for (int k = 0; k < 20; ++k) {
            int i = base + k;
            if (i < N_) { int o = excl + loc[k]; off[i] = o; cur[i] = o; }
        }
        if (t == 1023) off[N_] = sh[1023];
    } else {
        __shared__ int sh[64];
        int v = 0;
        if (t < 64) { v = bcnt[t]; sh[t] = v; }
        __syncthreads();
        for (int d = 1; d < 64; d <<= 1) {
            int val = (t >= d && t < 64) ? sh[t - d] : 0;
            __syncthreads();
            if (t < 64) sh[t] += val;
            __syncthreads();
        }
        if (t < 64) {
            int excl = sh[t] - v;
            boff[t] = excl; bcur[t] = excl;
            if (t == 63) boff[64] = sh[63];
        }
    }
}

// ================= fused fills =================
__global__ __launch_bounds__(256) void k_fills(const int* __restrict__ eidx,
                                               int* __restrict__ cur, int* __restrict__ rank,
                                               const int* __restrict__ batch,
                                               int* __restrict__ bcur, int* __restrict__ bperm) {
    int bid = blockIdx.x, t = threadIdx.x;
    if (bid < 1250) {
        int e = bid * 256 + t;
        rank[e] = atomicAdd(&cur[eidx[E_ + e]], 1);
    } else {
        int n = (bid - 1250) * 256 + t;
        if (n < N_) {
            int p = atomicAdd(&bcur[batch[n]], 1);
            bperm[p] = n;
        }
    }
}

// ================= main edge kernel: 64 edges/wave, x in registers + shfl, pk_fma epilogue =================
template <bool STORE>
__global__ __launch_bounds__(256) void k_edge(
    const unsigned short* __restrict__ efp, const int* __restrict__ eidx,
    const int* __restrict__ rank,
    const float* __restrict__ x, float* __restrict__ agg, unsigned short* __restrict__ msg,
    const unsigned short* __restrict__ w1r, const float* __restrict__ b1,
    const unsigned short* __restrict__ w2r, const float* __restrict__ b2,
    const unsigned short* __restrict__ w3r, const float* __restrict__ b3) {
    __shared__ float s_b3[1024];                          // 4 KB (block-shared)
    __shared__ __align__(16) unsigned short s_h[4][640];  // per-wave transpose buf, stride 40

    const int t = threadIdx.x;
    for (int k = t; k < 1024; k += 256) s_b3[k] = b3[k];

    const int wave = t >> 6, lane = t & 63;
    const int q = lane >> 4, e = lane & 15;
    const int ebase = (blockIdx.x * 4 + wave) * 64;

    // x[src] fragments in registers: lane (q,e) holds x[src(g,e)][q*8 .. q*8+7]
    F4 xfa[4], xfb[4];
    for (int g = 0; g < 4; ++g) {
        int srce = eidx[ebase + g * 16 + e];
        const float* xp = x + srce * 32 + q * 8;
        xfa[g].v = *(const f4*)xp;
        xfb[g].v = *(const f4*)(xp + 4);
    }

    // loop-invariant W1^T / W2^T fragments (pre-repacked) + bias regs
    U8 w1f[2], w2f[2];
    float b1v[2][4], b2v[2][4];
    for (int tau = 0; tau < 2; ++tau) {
        w1f[tau].u = *(const u4*)(w1r + tau * 512 + lane * 8);
        w2f[tau].u = *(const u4*)(w2r + tau * 512 + lane * 8);
        for (int r = 0; r < 4; ++r) {
            b1v[tau][r] = b1[tau * 16 + q * 4 + r];
            b2v[tau][r] = b2[tau * 16 + q * 4 + r];
        }
    }

    const f4 z4 = {0.f, 0.f, 0.f, 0.f};
    short8 h2f[4];

    // per-g MLP: within-wave LDS traffic only -> wave-local waits
    for (int g = 0; g < 4; ++g) {
        U8 ef;
        if (q == 0) ef.u = *(const u4*)(efp + (size_t)(ebase + g * 16 + e) * 8);
        else { u4 zz = {0u, 0u, 0u, 0u}; ef.u = zz; }

        f4 c0 = MFMA_B16(w1f[0].v, ef.v, z4);
        f4 c1 = MFMA_B16(w1f[1].v, ef.v, z4);
        us4 pk;
        for (int r = 0; r < 4; ++r) pk[r] = f2bs(fmaxf(c0[r] + b1v[0][r], 0.f));
        *(us4*)&s_h[wave][e * 40 + q * 4] = pk;
        for (int r = 0; r < 4; ++r) pk[r] = f2bs(fmaxf(c1[r] + b1v[1][r], 0.f));
        *(us4*)&s_h[wave][e * 40 + 16 + q * 4] = pk;
        WAVE_LDS_WAIT();
        short8 h1f = *(const short8*)&s_h[wave][e * 40 + q * 8];
        c0 = MFMA_B16(w2f[0].v, h1f, z4);
        c1 = MFMA_B16(w2f[1].v, h1f, z4);
        for (int r = 0; r < 4; ++r) pk[r] = f2bs(fmaxf(c0[r] + b2v[0][r], 0.f));
        *(us4*)&s_h[wave][e * 40 + q * 4] = pk;
        for (int r = 0; r < 4; ++r) pk[r] = f2bs(fmaxf(c1[r] + b2v[1][r], 0.f));
        *(us4*)&s_h[wave][e * 40 + 16 + q * 4] = pk;
        WAVE_LDS_WAIT();
        h2f[g] = *(const short8*)&s_h[wave][e * 40 + q * 8];
        WAVE_LDS_WAIT();
    }

    __syncthreads();  // s_b3 visibility

    F4 macc[4][2];
    for (int g = 0; g < 4; ++g) { macc[g][0].v = z4; macc[g][1].v = z4; }

#pragma unroll 1
    for (int ho = 0; ho < 4; ++ho) {
        int srcl = ho * 16 + e;
#pragma unroll
        for (int hj = 0; hj < 8; ++hj) {
            int h = ho * 8 + hj;
            short8 a0 = *(const short8*)(w3r + h * 1024 + lane * 8);
            short8 a1 = *(const short8*)(w3r + h * 1024 + 512 + lane * 8);
            f4 ci0 = *(const f4*)&s_b3[h * 32 + q * 4];
            f4 ci1 = *(const f4*)&s_b3[h * 32 + 16 + q * 4];
            for (int g = 0; g < 4; ++g) {
                float xsrc = (hj < 4) ? xfa[g].f[hj] : xfb[g].f[hj - 4];
                float xv = __shfl(xsrc, srcl);
                F4 d0, d1, m0, m1;
                d0.v = MFMA_B16(a0, h2f[g], ci0);
                d1.v = MFMA_B16(a1, h2f[g], ci1);
                for (int r = 0; r < 4; ++r) {
                    m0.f[r] = fmaxf(d0.f[r], 0.f);
                    m1.f[r] = fmaxf(d1.f[r], 0.f);
                }
                f2v xv2 = {xv, xv};
                macc[g][0].h[0] = __builtin_elementwise_fma(m0.h[0], xv2, macc[g][0].h[0]);
                macc[g][0].h[1] = __builtin_elementwise_fma(m0.h[1], xv2, macc[g][0].h[1]);
                macc[g][1].h[0] = __builtin_elementwise_fma(m1.h[0], xv2, macc[g][1].h[0]);
                macc[g][1].h[1] = __builtin_elementwise_fma(m1.h[1], xv2, macc[g][1].h[1]);
            }
        }
    }

    if (STORE) {
        for (int g = 0; g < 4; ++g) {
            int rk = rank[ebase + g * 16 + e];
            unsigned short* mp = msg + (size_t)rk * 32 + q * 4;
            for (int p = 0; p < 2; ++p) {
                us4 pk;
                for (int r = 0; r < 4; ++r) pk[r] = f2bs(macc[g][p].f[r]);
                *(us4*)(mp + p * 16) = pk;
            }
        }
    } else {
        for (int g = 0; g < 4; ++g) {
            int dste = eidx[E_ + ebase + g * 16 + e];
            float* ap = agg + dste * 32 + q * 4;
            for (int p = 0; p < 2; ++p)
                for (int r = 0; r < 4; ++r)
                    atomicAdd(ap + p * 16 + r, macc[g][p].f[r]);
        }
    }
}

// ================= gather: one wave per node, contiguous u4 streaming =================
__global__ __launch_bounds__(256) void k_gather(const unsigned short* __restrict__ msg,
                                                const int* __restrict__ off,
                                                const float* __restrict__ cb,
                                                float* __restrict__ x) {
    int wave = threadIdx.x >> 6, lane = threadIdx.x & 63;
    int n = blockIdx.x * 4 + wave;
    if (n >= N_) return;
    int j0 = off[n], j1 = off[n + 1];
    const unsigned short* base = msg + (size_t)j0 * 32;
    int nchunk = (j1 - j0) * 4;  // 16B chunks; row=64B so always whole chunks
    float a[8] = {0.f, 0.f, 0.f, 0.f, 0.f, 0.f, 0.f, 0.f};
    for (int it = lane; it < nchunk; it += 64) {
        u4 v = *(const u4*)(base + it * 8);
        for (int m = 0; m < 4; ++m) {
            unsigned int w = v[m];
            a[2 * m]     += __uint_as_float(w << 16);
            a[2 * m + 1] += __uint_as_float(w & 0xffff0000u);
        }
    }
    // lanes sharing (lane&3) hold the same 8 channels -> xor-reduce over 4,8,16,32
    for (int d = 4; d < 64; d <<= 1)
        for (int m = 0; m < 8; ++m)
            a[m] += __shfl_xor(a[m], d);
    if (lane < 4) {
        int c0 = lane * 8;
        float* xp = x + n * 32 + c0;
        F4 xa, xb2;
        xa.v = *(const f4*)xp;
        xb2.v = *(const f4*)(xp + 4);
        for (int i = 0; i < 4; ++i) {
            xa.f[i]  += fmaxf(a[i] + cb[c0 + i], 0.f);
            xb2.f[i] += fmaxf(a[4 + i] + cb[c0 + 4 + i], 0.f);
        }
        *(f4*)xp = xa.v;
        *(f4*)(xp + 4) = xb2.v;
    }
}

__device__ __forceinline__ float selu_(float v) {
    return 1.0507009873554805f * (v > 0.f ? v : 1.6732632423543772f * (expf(v) - 1.f));
}

// ================= fused pooling + head MLP + IDX gather =================
__global__ __launch_bounds__(256) void k_pool_head(const float* __restrict__ x,
                                                   const int* __restrict__ boff,
                                                   const int* __restrict__ bperm,
                                                   const float* __restrict__ W1, const float* __restrict__ b1,
                                                   const float* __restrict__ W2, const float* __restrict__ b2,
                                                   const float* __restrict__ W3, const float* __restrict__ b3,
                                                   const float* __restrict__ W4, const float* __restrict__ b4,
                                                   float* __restrict__ out) {
    __shared__ float sp[8][32];
    __shared__ float s0[32], s1[128], s2[64], s3[32], s4[21];
    int b = blockIdx.x, t = threadIdx.x, c = t & 31, slot = t >> 5;
    int j0 = boff[b], j1 = boff[b + 1];
    float a = 0.f;
    for (int j = j0 + slot; j < j1; j += 8)
        a += x[bperm[j] * 32 + c];
    sp[slot][c] = a;
    __syncthreads();
    if (t < 32) {
        float s = 0.f;
        for (int k = 0; k < 8; ++k) s += sp[k][t];
        s0[t] = s / fmaxf((float)(j1 - j0), 1.f);
    }
    __syncthreads();
    if (t < 128) {
        float v = b1[t];
        for (int cc = 0; cc < 32; ++cc) v += s0[cc] * W1[cc * 128 + t];
        s1[t] = selu_(v);
    }
    __syncthreads();
    if (t < 64) {
        float v = b2[t];
        for (int cc = 0; cc < 128; ++cc) v += s1[cc] * W2[cc * 64 + t];
        s2[t] = selu_(v);
    }
    __syncthreads();
    if (t < 32) {
        float v = b3[t];
        for (int cc = 0; cc < 64; ++cc) v += s2[cc] * W3[cc * 32 + t];
        s3[t] = selu_(v);
    }
    __syncthreads();
    if (t < 21) {
        float v = b4[t];
        for (int cc = 0; cc < 32; ++cc) v += s3[cc] * W4[cc * 21 + t];
        s4[t] = v;
    }
    __syncthreads();
    if (t < 36) out[b * 36 + t] = s4[c_IDX[t]];
}

// ================= fallback helpers (atomic path) =================
__global__ __launch_bounds__(256) void k_init_fb(const float* __restrict__ na,
                                                 const float* __restrict__ eW,
                                                 const float* __restrict__ eb,
                                                 float* __restrict__ x, float* __restrict__ agg) {
    int tid = blockIdx.x * 256 + threadIdx.x;
    int n = tid >> 5, c = tid & 31;
    x[tid] = na[n] * eW[c] + eb[c];
    agg[tid] = 0.f;
}

__global__ __launch_bounds__(256) void k_prep_fb(const float* __restrict__ pos,
                                                 const float* __restrict__ shifts,
                                                 const float* __restrict__ eattr,
                                                 const int* __restrict__ eidx,
                                                 unsigned short* __restrict__ efp) {
    int e = blockIdx.x * 256 + threadIdx.x;
    int s = eidx[e], d = eidx[E_ + e];
    float vx = pos[d * 3 + 0] - pos[s * 3 + 0] + shifts[e * 3 + 0];
    float vy = pos[d * 3 + 1] - pos[s * 3 + 1] + shifts[e * 3 + 1];
    float vz = pos[d * 3 + 2] - pos[s * 3 + 2] + shifts[e * 3 + 2];
    float ln = sqrtf(vx * vx + vy * vy + vz * vz);
    U8 o;
    o.us[0] = f2bs(vx); o.us[1] = f2bs(vy); o.us[2] = f2bs(vz);
    o.us[3] = f2bs(ln); o.us[4] = f2bs(eattr[e]);
    o.us[5] = 0; o.us[6] = 0; o.us[7] = 0;
    *(u4*)(efp + (size_t)e * 8) = o.u;
}

__global__ __launch_bounds__(256) void k_repack_fb(const float* __restrict__ w3,
                                                   unsigned short* __restrict__ w3r,
                                                   const float* __restrict__ w1,
                                                   const float* __restrict__ w2,
                                                   unsigned short* __restrict__ w1r,
                                                   unsigned short* __restrict__ w2r) {
    int tid = blockIdx.x * 256 + threadIdx.x;
    if (tid < 12288) {
        int l = tid & 63, t2 = (tid >> 6) & 63, i = tid >> 12;
        int q = l >> 4, m = l & 15;
        U8 o;
        for (int j = 0; j < 8; ++j) {
            int k = q * 8 + j;
            o.us[j] = f2bs(w3[(i * 32 + k) * 1024 + t2 * 16 + m]);
        }
        *(u4*)(w3r + (size_t)tid * 8) = o.u;
    } else if (tid < 13056) {
        int t2 = tid - 12288;
        bool isw2 = t2 >= 384;
        int idx = isw2 ? t2 - 384 : t2;   // FIX: 384 not pow2; no & mask
        int i = idx >> 7, tau = (idx >> 6) & 1, l = idx & 63;
        int q = l >> 4, m = l & 15;
        U8 o;
        for (int j = 0; j < 8; ++j) {
            int k = q * 8 + j;
            if (!isw2) o.us[j] = (k < 5) ? f2bs(w1[i * 160 + k * 32 + tau * 16 + m]) : (unsigned short)0;
            else       o.us[j] = f2bs(w2[i * 1024 + k * 32 + tau * 16 + m]);
        }
        unsigned short* dst = (isw2 ? w2r : w1r) + i * 1024 + tau * 512 + l * 8;
        *(u4*)dst = o.u;
    }
}

__global__ __launch_bounds__(256) void k_node(float* __restrict__ x, float* __restrict__ agg,
                                              const float* __restrict__ cb) {
    int tid = blockIdx.x * 256 + threadIdx.x;
    int c = tid & 31;
    float a = agg[tid] + cb[c];
    x[tid] += fmaxf(a, 0.f);
    agg[tid] = 0.f;
}

__global__ __launch_bounds__(256) void k_zero_pool(float* __restrict__ pooled, int* __restrict__ cnt) {
    int tid = blockIdx.x * 256 + threadIdx.x;
    if (tid < 2048) pooled[tid] = 0.f;
    else if (tid < 2112) cnt[tid - 2048] = 0;
}

__global__ __launch_bounds__(256) void k_pool(const float* __restrict__ x, const int* __restrict__ batch,
                                              float* __restrict__ pooled, int* __restrict__ cnt) {
    int tid = blockIdx.x * 256 + threadIdx.x;
    int n = tid >> 5, c = tid & 31;
    int b = batch[n];
    atomicAdd(&pooled[b * 32 + c], x[tid]);
    if (c == 0) atomicAdd(&cnt[b], 1);
}

__global__ __launch_bounds__(128) void k_head(const float* __restrict__ pooled, const int* __restrict__ cnt,
                                              const float* __restrict__ W1, const float* __restrict__ b1,
                                              const float* __restrict__ W2, const float* __restrict__ b2,
                                              const float* __restrict__ W3, const float* __restrict__ b3,
                                              const float* __restrict__ W4, const float* __restrict__ b4,
                                              float* __restrict__ out) {
    __shared__ float s0[32], s1[128], s2[64], s3[32], s4[21];
    int b = blockIdx.x, t = threadIdx.x;
    if (t < 32) s0[t] = pooled[b * 32 + t] / fmaxf((float)cnt[b], 1.f);
    __syncthreads();
    {
        float a = b1[t];
        for (int c = 0; c < 32; ++c) a += s0[c] * W1[c * 128 + t];
        s1[t] = selu_(a);
    }
    __syncthreads();
    if (t < 64) {
        float a = b2[t];
        for (int c = 0; c < 128; ++c) a += s1[c] * W2[c * 64 + t];
        s2[t] = selu_(a);
    }
    __syncthreads();
    if (t < 32) {
        float a = b3[t];
        for (int c = 0; c < 64; ++c) a += s2[c] * W3[c * 32 + t];
        s3[t] = selu_(a);
    }
    __syncthreads();
    if (t < 21) {
        float a = b4[t];
        for (int c = 0; c < 32; ++c) a += s3[c] * W4[c * 21 + t];
        s4[t] = a;
    }
    __syncthreads();
    if (t < 36) out[b * 36 + t] = s4[c_IDX[t]];
}

extern "C" void kernel_launch(void* const* d_in, const int* in_sizes, int n_in,
                              void* d_out, int out_size, void* d_ws, size_t ws_size,
                              hipStream_t stream) {
    const float* na     = (const float*)d_in[0];
    const float* pos    = (const float*)d_in[1];
    const float* shifts = (const float*)d_in[2];
    const float* eattr  = (const float*)d_in[3];
    const int*   eidx   = (const int*)d_in[4];
    const int*   batch  = (const int*)d_in[5];
    const float* embW   = (const float*)d_in[6];
    const float* embB   = (const float*)d_in[7];
    const float* eW1    = (const float*)d_in[8];
    const float* eb1    = (const float*)d_in[9];
    const float* eW2    = (const float*)d_in[10];
    const float* eb2    = (const float*)d_in[11];
    const float* eW3    = (const float*)d_in[12];
    const float* eb3    = (const float*)d_in[13];
    const float* cvb    = (const float*)d_in[14];
    const float* hW1    = (const float*)d_in[15];
    const float* hb1    = (const float*)d_in[16];
    const float* hW2    = (const float*)d_in[17];
    const float* hb2    = (const float*)d_in[18];
    const float* hW3    = (const float*)d_in[19];
    const float* hb3    = (const float*)d_in[20];
    const float* hW4    = (const float*)d_in[21];
    const float* hb4    = (const float*)d_in[22];

    // layout: x | deg | bcnt | off | cur | rank | boff | bcur | bperm | efp | w3r | w1r | w2r | msg
    const size_t need_csr = (size_t)640000 * 4
                          + (size_t)(20000 + 64 + 20004 + 20000 + 320000 + 68 + 64 + 20000) * 4
                          + ((size_t)E_ * 8 + 98304 + 3072 + 3072 + (size_t)E_ * 32) * 2;

    if (ws_size >= need_csr) {
        char* ws = (char*)d_ws;
        float* x      = (float*)ws;                              // 640000 f32
        int*   deg    = (int*)(x + 640000);                      // 20000
        int*   bcnt   = deg + 20000;                             // 64 (contiguous with deg)
        int*   off    = bcnt + 64;                               // 20001 (pad 20004)
        int*   cur    = off + 20004;                             // 20000
        int*   rank   = cur + 20000;                             // 320000
        int*   boff   = rank + 320000;                           // 65 (pad 68)
        int*   bcur   = boff + 68;                               // 64
        int*   bperm  = bcur + 64;                               // 20000
        unsigned short* efp = (unsigned short*)(bperm + 20000);  // E_*8 bf16
        unsigned short* w3r = efp + (size_t)E_ * 8;              // 98304 bf16
        unsigned short* w1r = w3r + 98304;                       // 3072 bf16
        unsigned short* w2r = w1r + 3072;                        // 3072 bf16
        unsigned short* msg = w2r + 3072;                        // E_*32 bf16

        k_setup<<<3801, 256, 0, stream>>>(na, embW, embB, x, deg,
                                          pos, shifts, eattr, eidx, efp,
                                          eW3, w3r, eW1, eW2, w1r, w2r);
        k_hists<<<1329, 256, 0, stream>>>(eidx, deg, batch, bcnt);
        k_scans<<<2, 1024, 0, stream>>>(deg, off, cur, bcnt, boff, bcur);
        k_fills<<<1329, 256, 0, stream>>>(eidx, cur, rank, batch, bcur, bperm);

        for (int i = 0; i < 3; ++i) {
            k_edge<true><<<1250, 256, 0, stream>>>(efp, eidx, rank, x, nullptr, msg,
                                                   w1r + i * 1024, eb1 + i * 32,
                                                   w2r + i * 1024, eb2 + i * 32,
                                                   w3r + i * 32768, eb3 + i * 1024);
            k_gather<<<5000, 256, 0, stream>>>(msg, off, cvb + i * 32, x);
        }

        k_pool_head<<<64, 256, 0, stream>>>(x, boff, bperm,
                                            hW1, hb1, hW2, hb2, hW3, hb3, hW4, hb4,
                                            (float*)d_out);
    } else {
        // fallback: atomic scatter path
        char* ws = (char*)d_ws;
        float* x      = (float*)ws;                           // 640000 f32
        float* agg    = x + 640000;                           // 640000 f32
        float* pooled = agg + 640000;                         // 2048 f32
        int*   cnt    = (int*)(pooled + 2048);                // 64
        unsigned short* efp = (unsigned short*)(cnt + 64);    // E_*8 bf16
        unsigned short* w3r = efp + (size_t)E_ * 8;           // 98304 bf16
        unsigned short* w1r = w3r + 98304;                    // 3072
        unsigned short* w2r = w1r + 3072;                     // 3072

        k_init_fb<<<2500, 256, 0, stream>>>(na, embW, embB, x, agg);
        k_prep_fb<<<1250, 256, 0, stream>>>(pos, shifts, eattr, eidx, efp);
        k_repack_fb<<<51, 256, 0, stream>>>(eW3, w3r, eW1, eW2, w1r, w2r);
        k_zero_pool<<<9, 256, 0, stream>>>(pooled, cnt);

        for (int i = 0; i < 3; ++i) {
            k_edge<false><<<1250, 256, 0, stream>>>(efp, eidx, nullptr, x, agg, nullptr,
                                                    w1r + i * 1024, eb1 + i * 32,
                                                    w2r + i * 1024, eb2 + i * 32,
                                                    w3r + i * 32768, eb3 + i * 1024);
            k_node<<<2500, 256, 0, stream>>>(x, agg, cvb + i * 32);
        }

        k_pool<<<2500, 256, 0, stream>>>(x, batch, pooled, cnt);
        k_head<<<64, 128, 0, stream>>>(pooled, cnt, hW1, hb1, hW2, hb2, hW3, hb3, hW4, hb4,
                                       (float*)d_out);
    }
}

// Round 8
// 380.942 us; speedup vs baseline: 1.7361x; 1.1854x over previous
//
#include <hip/hip_runtime.h>
#include <hip/hip_bf16.h>

#define N_ 20000
#define E_ 320000
#define B_ 64

typedef __attribute__((ext_vector_type(8))) short short8;
typedef __attribute__((ext_vector_type(4))) float f4;
typedef __attribute__((ext_vector_type(2))) float f2v;
typedef __attribute__((ext_vector_type(4))) unsigned int u4;
typedef __attribute__((ext_vector_type(4))) unsigned short us4;

union U8 { short s[8]; unsigned short us[8]; short8 v; u4 u; };
union F4 { f4 v; f2v h[2]; float f[4]; };

__device__ __forceinline__ float bs2f(unsigned short s) {
    return __uint_as_float(((unsigned int)s) << 16);
}
__device__ __forceinline__ unsigned short f2bs(float f) {
    unsigned int u = __float_as_uint(f);
    unsigned int r = u + 0x7FFFu + ((u >> 16) & 1u);  // round-to-nearest-even
    return (unsigned short)(r >> 16);
}

// wave-local LDS drain: s_h/s_x are per-wave buffers, no block barrier needed
#define WAVE_LDS_WAIT() asm volatile("s_waitcnt lgkmcnt(0)" ::: "memory")

#define MFMA_B16(a, b, c) __builtin_amdgcn_mfma_f32_16x16x32_bf16(a, b, c, 0, 0, 0)

__device__ __constant__ int c_IDX[36] = {
    0,1,2,3,4,5, 1,6,7,8,9,10, 2,7,11,12,13,14,
    3,8,12,15,16,17, 4,9,13,16,18,19, 5,10,14,17,19,20};

// ====== fused setup: init x | edge_prep + deg hist | repack w3 | repack w1/w2 | batch hist ======
// deg/bcnt must be zeroed (hipMemsetAsync) BEFORE this kernel.
__global__ __launch_bounds__(256) void k_setup(
    const float* __restrict__ na, const float* __restrict__ eW, const float* __restrict__ eb,
    float* __restrict__ x, int* __restrict__ deg, int* __restrict__ bcnt,
    const float* __restrict__ pos, const float* __restrict__ shifts, const float* __restrict__ eattr,
    const int* __restrict__ eidx, unsigned short* __restrict__ efp,
    const float* __restrict__ w3, unsigned short* __restrict__ w3r,
    const float* __restrict__ w1, const float* __restrict__ w2,
    unsigned short* __restrict__ w1r, unsigned short* __restrict__ w2r,
    const int* __restrict__ batch) {
    int bid = blockIdx.x, t = threadIdx.x;
    if (bid < 2500) {
        int tid = bid * 256 + t;  // < 640000 exact
        int n = tid >> 5, c = tid & 31;
        x[tid] = na[n] * eW[c] + eb[c];
    } else if (bid < 3750) {
        int e = (bid - 2500) * 256 + t;  // < E_ exact
        int s = eidx[e], d = eidx[E_ + e];
        float vx = pos[d * 3 + 0] - pos[s * 3 + 0] + shifts[e * 3 + 0];
        float vy = pos[d * 3 + 1] - pos[s * 3 + 1] + shifts[e * 3 + 1];
        float vz = pos[d * 3 + 2] - pos[s * 3 + 2] + shifts[e * 3 + 2];
        float ln = sqrtf(vx * vx + vy * vy + vz * vz);
        U8 o;
        o.us[0] = f2bs(vx); o.us[1] = f2bs(vy); o.us[2] = f2bs(vz);
        o.us[3] = f2bs(ln); o.us[4] = f2bs(eattr[e]);
        o.us[5] = 0; o.us[6] = 0; o.us[7] = 0;
        *(u4*)(efp + (size_t)e * 8) = o.u;
        atomicAdd(&deg[d], 1);  // node histogram fused here
    } else if (bid < 3798) {
        int tid = (bid - 3750) * 256 + t;  // < 12288 exact
        int l = tid & 63, t2 = (tid >> 6) & 63, i = tid >> 12;
        int q = l >> 4, m = l & 15;
        U8 o;
        for (int j = 0; j < 8; ++j) {
            int k = q * 8 + j;
            o.us[j] = f2bs(w3[(i * 32 + k) * 1024 + t2 * 16 + m]);
        }
        *(u4*)(w3r + (size_t)tid * 8) = o.u;
    } else if (bid < 3801) {
        int tid = (bid - 3798) * 256 + t;  // < 768 exact
        bool isw2 = tid >= 384;
        int idx = isw2 ? tid - 384 : tid;
        int i = idx >> 7;            // layer
        int tau = (idx >> 6) & 1;
        int l = idx & 63;
        int q = l >> 4, m = l & 15;
        U8 o;
        for (int j = 0; j < 8; ++j) {
            int k = q * 8 + j;
            if (!isw2) o.us[j] = (k < 5) ? f2bs(w1[i * 160 + k * 32 + tau * 16 + m]) : (unsigned short)0;
            else       o.us[j] = f2bs(w2[i * 1024 + k * 32 + tau * 16 + m]);
        }
        unsigned short* dst = (isw2 ? w2r : w1r) + i * 1024 + tau * 512 + l * 8;
        *(u4*)dst = o.u;
    } else {
        __shared__ int s[64];
        if (t < 64) s[t] = 0;
        __syncthreads();
        int n = (bid - 3801) * 256 + t;
        if (n < N_) atomicAdd(&s[batch[n]], 1);
        __syncthreads();
        if (t < 64 && s[t]) atomicAdd(&bcnt[t], s[t]);
    }
}

// ================= fused scans =================
__global__ __launch_bounds__(1024) void k_scans(const int* __restrict__ deg,
                                                int* __restrict__ off, int* __restrict__ cur,
                                                const int* __restrict__ bcnt,
                                                int* __restrict__ boff, int* __restrict__ bcur) {
    int t = threadIdx.x;
    if (blockIdx.x == 0) {
        __shared__ int sh[1024];
        int base = t * 20;
        int loc[20]; int s = 0;
        for (int k = 0; k < 20; ++k) {
            int i = base + k;
            int v = (i < N_) ? deg[i] : 0;
            loc[k] = s; s += v;
        }
        sh[t] = s;
        __syncthreads();
        for (int d = 1; d < 1024; d <<= 1) {
            int val = (t >= d) ? sh[t - d] : 0;
            __syncthreads();
            sh[t] += val;
            __syncthreads();
        }
        int excl = sh[t] - s;
        for (int k = 0; k < 20; ++k) {
            int i = base + k;
            if (i < N_) { int o = excl + loc[k]; off[i] = o; cur[i] = o; }
        }
        if (t == 1023) off[N_] = sh[1023];
    } else {
        __shared__ int sh[64];
        int v = 0;
        if (t < 64) { v = bcnt[t]; sh[t] = v; }
        __syncthreads();
        for (int d = 1; d < 64; d <<= 1) {
            int val = (t >= d && t < 64) ? sh[t - d] : 0;
            __syncthreads();
            if (t < 64) sh[t] += val;
            __syncthreads();
        }
        if (t < 64) {
            int excl = sh[t] - v;
            boff[t] = excl; bcur[t] = excl;
            if (t == 63) boff[64] = sh[63];
        }
    }
}

// ================= fused fills =================
__global__ __launch_bounds__(256) void k_fills(const int* __restrict__ eidx,
                                               int* __restrict__ cur, int* __restrict__ rank,
                                               const int* __restrict__ batch,
                                               int* __restrict__ bcur, int* __restrict__ bperm) {
    int bid = blockIdx.x, t = threadIdx.x;
    if (bid < 1250) {
        int e = bid * 256 + t;
        rank[e] = atomicAdd(&cur[eidx[E_ + e]], 1);
    } else {
        int n = (bid - 1250) * 256 + t;
        if (n < N_) {
            int p = atomicAdd(&bcur[batch[n]], 1);
            bperm[p] = n;
        }
    }
}

// ================= main edge kernel: 32 edges/wave, grid 2500, occupancy-first =================
template <bool STORE>
__global__ __launch_bounds__(256, 6) void k_edge(
    const unsigned short* __restrict__ efp, const int* __restrict__ eidx,
    const int* __restrict__ rank,
    const float* __restrict__ x, float* __restrict__ agg, unsigned short* __restrict__ msg,
    const unsigned short* __restrict__ w1r, const float* __restrict__ b1,
    const unsigned short* __restrict__ w2r, const float* __restrict__ b2,
    const unsigned short* __restrict__ w3r, const float* __restrict__ b3) {
    __shared__ float s_b3[1024];                          // 4 KB (block-shared)
    __shared__ __align__(16) unsigned short s_h[4][640];  // per-wave transpose buf, stride 40
    __shared__ __align__(16) unsigned short s_x[4][2][640]; // per-wave bf16 x tiles, stride 40

    const int t = threadIdx.x;
    for (int k = t; k < 1024; k += 256) s_b3[k] = b3[k];

    const int wave = t >> 6, lane = t & 63;
    const int q = lane >> 4, e = lane & 15;
    const int ebase = (blockIdx.x * 4 + wave) * 32;

    // stage x[src] tiles as bf16 (per-wave LDS)
    for (int g = 0; g < 2; ++g) {
        int srce = eidx[ebase + g * 16 + e];
        const float* xp = x + srce * 32 + q * 8;
        F4 xa, xb2;
        xa.v = *(const f4*)xp;
        xb2.v = *(const f4*)(xp + 4);
        us4 p0, p1;
        for (int r = 0; r < 4; ++r) { p0[r] = f2bs(xa.f[r]); p1[r] = f2bs(xb2.f[r]); }
        unsigned short* dp = &s_x[wave][g][e * 40 + q * 8];
        *(us4*)dp = p0;
        *(us4*)(dp + 4) = p1;
    }

    // loop-invariant W1^T / W2^T fragments (pre-repacked) + bias regs
    U8 w1f[2], w2f[2];
    float b1v[2][4], b2v[2][4];
    for (int tau = 0; tau < 2; ++tau) {
        w1f[tau].u = *(const u4*)(w1r + tau * 512 + lane * 8);
        w2f[tau].u = *(const u4*)(w2r + tau * 512 + lane * 8);
        for (int r = 0; r < 4; ++r) {
            b1v[tau][r] = b1[tau * 16 + q * 4 + r];
            b2v[tau][r] = b2[tau * 16 + q * 4 + r];
        }
    }

    const f4 z4 = {0.f, 0.f, 0.f, 0.f};
    short8 h2f[2];

    // per-g MLP: within-wave LDS traffic only -> wave-local waits
    for (int g = 0; g < 2; ++g) {
        U8 ef;
        if (q == 0) ef.u = *(const u4*)(efp + (size_t)(ebase + g * 16 + e) * 8);
        else { u4 zz = {0u, 0u, 0u, 0u}; ef.u = zz; }

        f4 c0 = MFMA_B16(w1f[0].v, ef.v, z4);
        f4 c1 = MFMA_B16(w1f[1].v, ef.v, z4);
        us4 pk;
        for (int r = 0; r < 4; ++r) pk[r] = f2bs(fmaxf(c0[r] + b1v[0][r], 0.f));
        *(us4*)&s_h[wave][e * 40 + q * 4] = pk;
        for (int r = 0; r < 4; ++r) pk[r] = f2bs(fmaxf(c1[r] + b1v[1][r], 0.f));
        *(us4*)&s_h[wave][e * 40 + 16 + q * 4] = pk;
        WAVE_LDS_WAIT();
        short8 h1f = *(const short8*)&s_h[wave][e * 40 + q * 8];
        c0 = MFMA_B16(w2f[0].v, h1f, z4);
        c1 = MFMA_B16(w2f[1].v, h1f, z4);
        for (int r = 0; r < 4; ++r) pk[r] = f2bs(fmaxf(c0[r] + b2v[0][r], 0.f));
        *(us4*)&s_h[wave][e * 40 + q * 4] = pk;
        for (int r = 0; r < 4; ++r) pk[r] = f2bs(fmaxf(c1[r] + b2v[1][r], 0.f));
        *(us4*)&s_h[wave][e * 40 + 16 + q * 4] = pk;
        WAVE_LDS_WAIT();
        h2f[g] = *(const short8*)&s_h[wave][e * 40 + q * 8];
        WAVE_LDS_WAIT();
    }

    __syncthreads();  // s_b3 visibility

    F4 macc[2][2];
    macc[0][0].v = z4; macc[0][1].v = z4; macc[1][0].v = z4; macc[1][1].v = z4;

#pragma unroll 4
    for (int h = 0; h < 32; ++h) {
        short8 a0 = *(const short8*)(w3r + h * 1024 + lane * 8);
        short8 a1 = *(const short8*)(w3r + h * 1024 + 512 + lane * 8);
        f4 ci0 = *(const f4*)&s_b3[h * 32 + q * 4];
        f4 ci1 = *(const f4*)&s_b3[h * 32 + 16 + q * 4];
        for (int g = 0; g < 2; ++g) {
            float xv = bs2f(s_x[wave][g][e * 40 + h]);
            F4 d0, d1, m0, m1;
            d0.v = MFMA_B16(a0, h2f[g], ci0);
            d1.v = MFMA_B16(a1, h2f[g], ci1);
            for (int r = 0; r < 4; ++r) {
                m0.f[r] = fmaxf(d0.f[r], 0.f);
                m1.f[r] = fmaxf(d1.f[r], 0.f);
            }
            f2v xv2 = {xv, xv};
            macc[g][0].h[0] = __builtin_elementwise_fma(m0.h[0], xv2, macc[g][0].h[0]);
            macc[g][0].h[1] = __builtin_elementwise_fma(m0.h[1], xv2, macc[g][0].h[1]);
            macc[g][1].h[0] = __builtin_elementwise_fma(m1.h[0], xv2, macc[g][1].h[0]);
            macc[g][1].h[1] = __builtin_elementwise_fma(m1.h[1], xv2, macc[g][1].h[1]);
        }
    }

    if (STORE) {
        for (int g = 0; g < 2; ++g) {
            int rk = rank[ebase + g * 16 + e];
            unsigned short* mp = msg + (size_t)rk * 32 + q * 4;
            for (int p = 0; p < 2; ++p) {
                us4 pk;
                for (int r = 0; r < 4; ++r) pk[r] = f2bs(macc[g][p].f[r]);
                *(us4*)(mp + p * 16) = pk;
            }
        }
    } else {
        for (int g = 0; g < 2; ++g) {
            int dste = eidx[E_ + ebase + g * 16 + e];
            float* ap = agg + dste * 32 + q * 4;
            for (int p = 0; p < 2; ++p)
                for (int r = 0; r < 4; ++r)
                    atomicAdd(ap + p * 16 + r, macc[g][p].f[r]);
        }
    }
}

// ================= gather: one wave per node, contiguous u4 streaming =================
__global__ __launch_bounds__(256) void k_gather(const unsigned short* __restrict__ msg,
                                                const int* __restrict__ off,
                                                const float* __restrict__ cb,
                                                float* __restrict__ x) {
    int wave = threadIdx.x >> 6, lane = threadIdx.x & 63;
    int n = blockIdx.x * 4 + wave;
    if (n >= N_) return;
    int j0 = off[n], j1 = off[n + 1];
    const unsigned short* base = msg + (size_t)j0 * 32;
    int nchunk = (j1 - j0) * 4;  // 16B chunks; row=64B so always whole chunks
    float a[8] = {0.f, 0.f, 0.f, 0.f, 0.f, 0.f, 0.f, 0.f};
    for (int it = lane; it < nchunk; it += 64) {
        u4 v = *(const u4*)(base + it * 8);
        for (int m = 0; m < 4; ++m) {
            unsigned int w = v[m];
            a[2 * m]     += __uint_as_float(w << 16);
            a[2 * m + 1] += __uint_as_float(w & 0xffff0000u);
        }
    }
    for (int d = 4; d < 64; d <<= 1)
        for (int m = 0; m < 8; ++m)
            a[m] += __shfl_xor(a[m], d);
    if (lane < 4) {
        int c0 = lane * 8;
        float* xp = x + n * 32 + c0;
        F4 xa, xb2;
        xa.v = *(const f4*)xp;
        xb2.v = *(const f4*)(xp + 4);
        for (int i = 0; i < 4; ++i) {
            xa.f[i]  += fmaxf(a[i] + cb[c0 + i], 0.f);
            xb2.f[i] += fmaxf(a[4 + i] + cb[c0 + 4 + i], 0.f);
        }
        *(f4*)xp = xa.v;
        *(f4*)(xp + 4) = xb2.v;
    }
}

__device__ __forceinline__ float selu_(float v) {
    return 1.0507009873554805f * (v > 0.f ? v : 1.6732632423543772f * (expf(v) - 1.f));
}

// ================= fused pooling (32 slots) + head MLP + IDX gather =================
__global__ __launch_bounds__(1024) void k_pool_head(const float* __restrict__ x,
                                                    const int* __restrict__ boff,
                                                    const int* __restrict__ bperm,
                                                    const float* __restrict__ W1, const float* __restrict__ b1,
                                                    const float* __restrict__ W2, const float* __restrict__ b2,
                                                    const float* __restrict__ W3, const float* __restrict__ b3,
                                                    const float* __restrict__ W4, const float* __restrict__ b4,
                                                    float* __restrict__ out) {
    __shared__ float sp[32][32];
    __shared__ float s0[32], s1[128], s2[64], s3[32], s4[21];
    int b = blockIdx.x, t = threadIdx.x, c = t & 31, slot = t >> 5;
    int j0 = boff[b], j1 = boff[b + 1];
    float a = 0.f;
    for (int j = j0 + slot; j < j1; j += 32)
        a += x[bperm[j] * 32 + c];
    sp[slot][c] = a;
    __syncthreads();
    if (t < 32) {
        float s = 0.f;
        for (int k = 0; k < 32; ++k) s += sp[k][t];
        s0[t] = s / fmaxf((float)(j1 - j0), 1.f);
    }
    __syncthreads();
    if (t < 128) {
        float v = b1[t];
        for (int cc = 0; cc < 32; ++cc) v += s0[cc] * W1[cc * 128 + t];
        s1[t] = selu_(v);
    }
    __syncthreads();
    if (t < 64) {
        float v = b2[t];
        for (int cc = 0; cc < 128; ++cc) v += s1[cc] * W2[cc * 64 + t];
        s2[t] = selu_(v);
    }
    __syncthreads();
    if (t < 32) {
        float v = b3[t];
        for (int cc = 0; cc < 64; ++cc) v += s2[cc] * W3[cc * 32 + t];
        s3[t] = selu_(v);
    }
    __syncthreads();
    if (t < 21) {
        float v = b4[t];
        for (int cc = 0; cc < 32; ++cc) v += s3[cc] * W4[cc * 21 + t];
        s4[t] = v;
    }
    __syncthreads();
    if (t < 36) out[b * 36 + t] = s4[c_IDX[t]];
}

// ================= fallback helpers (atomic path) =================
__global__ __launch_bounds__(256) void k_init_fb(const float* __restrict__ na,
                                                 const float* __restrict__ eW,
                                                 const float* __restrict__ eb,
                                                 float* __restrict__ x, float* __restrict__ agg) {
    int tid = blockIdx.x * 256 + threadIdx.x;
    int n = tid >> 5, c = tid & 31;
    x[tid] = na[n] * eW[c] + eb[c];
    agg[tid] = 0.f;
}

__global__ __launch_bounds__(256) void k_prep_fb(const float* __restrict__ pos,
                                                 const float* __restrict__ shifts,
                                                 const float* __restrict__ eattr,
                                                 const int* __restrict__ eidx,
                                                 unsigned short* __restrict__ efp) {
    int e = blockIdx.x * 256 + threadIdx.x;
    int s = eidx[e], d = eidx[E_ + e];
    float vx = pos[d * 3 + 0] - pos[s * 3 + 0] + shifts[e * 3 + 0];
    float vy = pos[d * 3 + 1] - pos[s * 3 + 1] + shifts[e * 3 + 1];
    float vz = pos[d * 3 + 2] - pos[s * 3 + 2] + shifts[e * 3 + 2];
    float ln = sqrtf(vx * vx + vy * vy + vz * vz);
    U8 o;
    o.us[0] = f2bs(vx); o.us[1] = f2bs(vy); o.us[2] = f2bs(vz);
    o.us[3] = f2bs(ln); o.us[4] = f2bs(eattr[e]);
    o.us[5] = 0; o.us[6] = 0; o.us[7] = 0;
    *(u4*)(efp + (size_t)e * 8) = o.u;
}

__global__ __launch_bounds__(256) void k_repack_fb(const float* __restrict__ w3,
                                                   unsigned short* __restrict__ w3r,
                                                   const float* __restrict__ w1,
                                                   const float* __restrict__ w2,
                                                   unsigned short* __restrict__ w1r,
                                                   unsigned short* __restrict__ w2r) {
    int tid = blockIdx.x * 256 + threadIdx.x;
    if (tid < 12288) {
        int l = tid & 63, t2 = (tid >> 6) & 63, i = tid >> 12;
        int q = l >> 4, m = l & 15;
        U8 o;
        for (int j = 0; j < 8; ++j) {
            int k = q * 8 + j;
            o.us[j] = f2bs(w3[(i * 32 + k) * 1024 + t2 * 16 + m]);
        }
        *(u4*)(w3r + (size_t)tid * 8) = o.u;
    } else if (tid < 13056) {
        int t2 = tid - 12288;
        bool isw2 = t2 >= 384;
        int idx = isw2 ? t2 - 384 : t2;
        int i = idx >> 7, tau = (idx >> 6) & 1, l = idx & 63;
        int q = l >> 4, m = l & 15;
        U8 o;
        for (int j = 0; j < 8; ++j) {
            int k = q * 8 + j;
            if (!isw2) o.us[j] = (k < 5) ? f2bs(w1[i * 160 + k * 32 + tau * 16 + m]) : (unsigned short)0;
            else       o.us[j] = f2bs(w2[i * 1024 + k * 32 + tau * 16 + m]);
        }
        unsigned short* dst = (isw2 ? w2r : w1r) + i * 1024 + tau * 512 + l * 8;
        *(u4*)dst = o.u;
    }
}

__global__ __launch_bounds__(256) void k_node(float* __restrict__ x, float* __restrict__ agg,
                                              const float* __restrict__ cb) {
    int tid = blockIdx.x * 256 + threadIdx.x;
    int c = tid & 31;
    float a = agg[tid] + cb[c];
    x[tid] += fmaxf(a, 0.f);
    agg[tid] = 0.f;
}

__global__ __launch_bounds__(256) void k_zero_pool(float* __restrict__ pooled, int* __restrict__ cnt) {
    int tid = blockIdx.x * 256 + threadIdx.x;
    if (tid < 2048) pooled[tid] = 0.f;
    else if (tid < 2112) cnt[tid - 2048] = 0;
}

__global__ __launch_bounds__(256) void k_pool(const float* __restrict__ x, const int* __restrict__ batch,
                                              float* __restrict__ pooled, int* __restrict__ cnt) {
    int tid = blockIdx.x * 256 + threadIdx.x;
    int n = tid >> 5, c = tid & 31;
    int b = batch[n];
    atomicAdd(&pooled[b * 32 + c], x[tid]);
    if (c == 0) atomicAdd(&cnt[b], 1);
}

__global__ __launch_bounds__(128) void k_head(const float* __restrict__ pooled, const int* __restrict__ cnt,
                                              const float* __restrict__ W1, const float* __restrict__ b1,
                                              const float* __restrict__ W2, const float* __restrict__ b2,
                                              const float* __restrict__ W3, const float* __restrict__ b3,
                                              const float* __restrict__ W4, const float* __restrict__ b4,
                                              float* __restrict__ out) {
    __shared__ float s0[32], s1[128], s2[64], s3[32], s4[21];
    int b = blockIdx.x, t = threadIdx.x;
    if (t < 32) s0[t] = pooled[b * 32 + t] / fmaxf((float)cnt[b], 1.f);
    __syncthreads();
    {
        float a = b1[t];
        for (int c = 0; c < 32; ++c) a += s0[c] * W1[c * 128 + t];
        s1[t] = selu_(a);
    }
    __syncthreads();
    if (t < 64) {
        float a = b2[t];
        for (int c = 0; c < 128; ++c) a += s1[c] * W2[c * 64 + t];
        s2[t] = selu_(a);
    }
    __syncthreads();
    if (t < 32) {
        float a = b3[t];
        for (int c = 0; c < 64; ++c) a += s2[c] * W3[c * 32 + t];
        s3[t] = selu_(a);
    }
    __syncthreads();
    if (t < 21) {
        float a = b4[t];
        for (int c = 0; c < 32; ++c) a += s3[c] * W4[c * 21 + t];
        s4[t] = a;
    }
    __syncthreads();
    if (t < 36) out[b * 36 + t] = s4[c_IDX[t]];
}

extern "C" void kernel_launch(void* const* d_in, const int* in_sizes, int n_in,
                              void* d_out, int out_size, void* d_ws, size_t ws_size,
                              hipStream_t stream) {
    const float* na     = (const float*)d_in[0];
    const float* pos    = (const float*)d_in[1];
    const float* shifts = (const float*)d_in[2];
    const float* eattr  = (const float*)d_in[3];
    const int*   eidx   = (const int*)d_in[4];
    const int*   batch  = (const int*)d_in[5];
    const float* embW   = (const float*)d_in[6];
    const float* embB   = (const float*)d_in[7];
    const float* eW1    = (const float*)d_in[8];
    const float* eb1    = (const float*)d_in[9];
    const float* eW2    = (const float*)d_in[10];
    const float* eb2    = (const float*)d_in[11];
    const float* eW3    = (const float*)d_in[12];
    const float* eb3    = (const float*)d_in[13];
    const float* cvb    = (const float*)d_in[14];
    const float* hW1    = (const float*)d_in[15];
    const float* hb1    = (const float*)d_in[16];
    const float* hW2    = (const float*)d_in[17];
    const float* hb2    = (const float*)d_in[18];
    const float* hW3    = (const float*)d_in[19];
    const float* hb3    = (const float*)d_in[20];
    const float* hW4    = (const float*)d_in[21];
    const float* hb4    = (const float*)d_in[22];

    // layout: x | deg | bcnt | off | cur | rank | boff | bcur | bperm | efp | w3r | w1r | w2r | msg
    const size_t need_csr = (size_t)640000 * 4
                          + (size_t)(20000 + 64 + 20004 + 20000 + 320000 + 68 + 64 + 20000) * 4
                          + ((size_t)E_ * 8 + 98304 + 3072 + 3072 + (size_t)E_ * 32) * 2;

    if (ws_size >= need_csr) {
        char* ws = (char*)d_ws;
        float* x      = (float*)ws;                              // 640000 f32
        int*   deg    = (int*)(x + 640000);                      // 20000
        int*   bcnt   = deg + 20000;                             // 64 (contiguous with deg)
        int*   off    = bcnt + 64;                               // 20001 (pad 20004)
        int*   cur    = off + 20004;                             // 20000
        int*   rank   = cur + 20000;                             // 320000
        int*   boff   = rank + 320000;                           // 65 (pad 68)
        int*   bcur   = boff + 68;                               // 64
        int*   bperm  = bcur + 64;                               // 20000
        unsigned short* efp = (unsigned short*)(bperm + 20000);  // E_*8 bf16
        unsigned short* w3r = efp + (size_t)E_ * 8;              // 98304 bf16
        unsigned short* w1r = w3r + 98304;                       // 3072 bf16
        unsigned short* w2r = w1r + 3072;                        // 3072 bf16
        unsigned short* msg = w2r + 3072;                        // E_*32 bf16

        hipMemsetAsync(deg, 0, (20000 + 64) * sizeof(int), stream);  // deg + bcnt
        k_setup<<<3880, 256, 0, stream>>>(na, embW, embB, x, deg, bcnt,
                                          pos, shifts, eattr, eidx, efp,
                                          eW3, w3r, eW1, eW2, w1r, w2r, batch);
        k_scans<<<2, 1024, 0, stream>>>(deg, off, cur, bcnt, boff, bcur);
        k_fills<<<1329, 256, 0, stream>>>(eidx, cur, rank, batch, bcur, bperm);

        for (int i = 0; i < 3; ++i) {
            k_edge<true><<<2500, 256, 0, stream>>>(efp, eidx, rank, x, nullptr, msg,
                                                   w1r + i * 1024, eb1 + i * 32,
                                                   w2r + i * 1024, eb2 + i * 32,
                                                   w3r + i * 32768, eb3 + i * 1024);
            k_gather<<<5000, 256, 0, stream>>>(msg, off, cvb + i * 32, x);
        }

        k_pool_head<<<64, 1024, 0, stream>>>(x, boff, bperm,
                                             hW1, hb1, hW2, hb2, hW3, hb3, hW4, hb4,
                                             (float*)d_out);
    } else {
        // fallback: atomic scatter path
        char* ws = (char*)d_ws;
        float* x      = (float*)ws;                           // 640000 f32
        float* agg    = x + 640000;                           // 640000 f32
        float* pooled = agg + 640000;                         // 2048 f32
        int*   cnt    = (int*)(pooled + 2048);                // 64
        unsigned short* efp = (unsigned short*)(cnt + 64);    // E_*8 bf16
        unsigned short* w3r = efp + (size_t)E_ * 8;           // 98304 bf16
        unsigned short* w1r = w3r + 98304;                    // 3072
        unsigned short* w2r = w1r + 3072;                     // 3072

        k_init_fb<<<2500, 256, 0, stream>>>(na, embW, embB, x, agg);
        k_prep_fb<<<1250, 256, 0, stream>>>(pos, shifts, eattr, eidx, efp);
        k_repack_fb<<<51, 256, 0, stream>>>(eW3, w3r, eW1, eW2, w1r, w2r);
        k_zero_pool<<<9, 256, 0, stream>>>(pooled, cnt);

        for (int i = 0; i < 3; ++i) {
            k_edge<false><<<2500, 256, 0, stream>>>(efp, eidx, nullptr, x, agg, nullptr,
                                                    w1r + i * 1024, eb1 + i * 32,
                                                    w2r + i * 1024, eb2 + i * 32,
                                                    w3r + i * 32768, eb3 + i * 1024);
            k_node<<<2500, 256, 0, stream>>>(x, agg, cvb + i * 32);
        }

        k_pool<<<2500, 256, 0, stream>>>(x, batch, pooled, cnt);
        k_head<<<64, 128, 0, stream>>>(pooled, cnt, hW1, hb1, hW2, hb2, hW3, hb3, hW4, hb4,
                                       (float*)d_out);
    }
}

// Round 9
// 377.833 us; speedup vs baseline: 1.7504x; 1.0082x over previous
//
#include <hip/hip_runtime.h>
#include <hip/hip_bf16.h>

#define N_ 20000
#define E_ 320000
#define B_ 64

typedef __attribute__((ext_vector_type(8))) short short8;
typedef __attribute__((ext_vector_type(4))) float f4;
typedef __attribute__((ext_vector_type(2))) float f2v;
typedef __attribute__((ext_vector_type(4))) unsigned int u4;
typedef __attribute__((ext_vector_type(4))) unsigned short us4;

union U8 { short s[8]; unsigned short us[8]; short8 v; u4 u; };
union F4 { f4 v; f2v h[2]; float f[4]; };

__device__ __forceinline__ float bs2f(unsigned short s) {
    return __uint_as_float(((unsigned int)s) << 16);
}
__device__ __forceinline__ unsigned short f2bs(float f) {
    unsigned int u = __float_as_uint(f);
    unsigned int r = u + 0x7FFFu + ((u >> 16) & 1u);  // round-to-nearest-even
    return (unsigned short)(r >> 16);
}
// packed f32x2 -> bf16x2 (v_cvt_pk_bf16_f32 on gfx950), low short = a
__device__ __forceinline__ unsigned int pk2(float a, float b) {
    __hip_bfloat162 h = __float22bfloat162_rn(make_float2(a, b));
    union { __hip_bfloat162 h2; unsigned int u; } cv;
    cv.h2 = h;
    return cv.u;
}

// wave-local LDS drain: s_h/s_x are per-wave buffers, no block barrier needed
#define WAVE_LDS_WAIT() asm volatile("s_waitcnt lgkmcnt(0)" ::: "memory")

#define MFMA_B16(a, b, c) __builtin_amdgcn_mfma_f32_16x16x32_bf16(a, b, c, 0, 0, 0)

__device__ __constant__ int c_IDX[36] = {
    0,1,2,3,4,5, 1,6,7,8,9,10, 2,7,11,12,13,14,
    3,8,12,15,16,17, 4,9,13,16,18,19, 5,10,14,17,19,20};

// ====== fused setup: init x (f4) | edge_prep + deg hist | repack w3 | repack w1/w2 | batch hist ======
// deg/bcnt must be zeroed (hipMemsetAsync) BEFORE this kernel.
__global__ __launch_bounds__(256) void k_setup(
    const float* __restrict__ na, const float* __restrict__ eW, const float* __restrict__ eb,
    float* __restrict__ x, int* __restrict__ deg, int* __restrict__ bcnt,
    const float* __restrict__ pos, const float* __restrict__ shifts, const float* __restrict__ eattr,
    const int* __restrict__ eidx, unsigned short* __restrict__ efp,
    const float* __restrict__ w3, unsigned short* __restrict__ w3r,
    const float* __restrict__ w1, const float* __restrict__ w2,
    unsigned short* __restrict__ w1r, unsigned short* __restrict__ w2r,
    const int* __restrict__ batch) {
    int bid = blockIdx.x, t = threadIdx.x;
    if (bid < 625) {
        int tid = bid * 256 + t;          // < 160000 exact
        int base = tid * 4;
        int n = tid >> 3, c = (tid & 7) * 4;
        float nv = na[n];
        F4 o;
        for (int r = 0; r < 4; ++r) o.f[r] = nv * eW[c + r] + eb[c + r];
        *(f4*)(x + base) = o.v;
    } else if (bid < 1875) {
        int e = (bid - 625) * 256 + t;    // < E_ exact
        int s = eidx[e], d = eidx[E_ + e];
        float vx = pos[d * 3 + 0] - pos[s * 3 + 0] + shifts[e * 3 + 0];
        float vy = pos[d * 3 + 1] - pos[s * 3 + 1] + shifts[e * 3 + 1];
        float vz = pos[d * 3 + 2] - pos[s * 3 + 2] + shifts[e * 3 + 2];
        float ln = sqrtf(vx * vx + vy * vy + vz * vz);
        u4 o;
        o[0] = pk2(vx, vy);
        o[1] = pk2(vz, ln);
        o[2] = pk2(eattr[e], 0.f);
        o[3] = 0u;
        *(u4*)(efp + (size_t)e * 8) = o;
        atomicAdd(&deg[d], 1);            // node histogram fused here
    } else if (bid < 1923) {
        int tid = (bid - 1875) * 256 + t; // < 12288 exact
        int l = tid & 63, t2 = (tid >> 6) & 63, i = tid >> 12;
        int q = l >> 4, m = l & 15;
        U8 o;
        for (int j = 0; j < 8; ++j) {
            int k = q * 8 + j;
            o.us[j] = f2bs(w3[(i * 32 + k) * 1024 + t2 * 16 + m]);
        }
        *(u4*)(w3r + (size_t)tid * 8) = o.u;
    } else if (bid < 1926) {
        int tid = (bid - 1923) * 256 + t; // < 768 exact
        bool isw2 = tid >= 384;
        int idx = isw2 ? tid - 384 : tid;
        int i = idx >> 7;                 // layer
        int tau = (idx >> 6) & 1;
        int l = idx & 63;
        int q = l >> 4, m = l & 15;
        U8 o;
        for (int j = 0; j < 8; ++j) {
            int k = q * 8 + j;
            if (!isw2) o.us[j] = (k < 5) ? f2bs(w1[i * 160 + k * 32 + tau * 16 + m]) : (unsigned short)0;
            else       o.us[j] = f2bs(w2[i * 1024 + k * 32 + tau * 16 + m]);
        }
        unsigned short* dst = (isw2 ? w2r : w1r) + i * 1024 + tau * 512 + l * 8;
        *(u4*)dst = o.u;
    } else {
        __shared__ int s[64];
        if (t < 64) s[t] = 0;
        __syncthreads();
        int n = (bid - 1926) * 256 + t;
        if (n < N_) atomicAdd(&s[batch[n]], 1);
        __syncthreads();
        if (t < 64 && s[t]) atomicAdd(&bcnt[t], s[t]);
    }
}

// ================= fused scans (shfl-based, 2 barriers) =================
__global__ __launch_bounds__(1024) void k_scans(const int* __restrict__ deg,
                                                int* __restrict__ off, int* __restrict__ cur,
                                                const int* __restrict__ bcnt,
                                                int* __restrict__ boff, int* __restrict__ bcur) {
    int t = threadIdx.x;
    if (blockIdx.x == 0) {
        __shared__ int shW[16];
        int base = t * 20;  // 1024*20 >= N_
        int loc[20]; int s = 0;
        for (int k = 0; k < 20; ++k) {
            int i = base + k;
            int v = (i < N_) ? deg[i] : 0;
            loc[k] = s; s += v;
        }
        int lane = t & 63, wv = t >> 6;
        int v = s;
        for (int d = 1; d < 64; d <<= 1) {
            int u = __shfl_up(v, d);
            if (lane >= d) v += u;
        }
        if (lane == 63) shW[wv] = v;
        __syncthreads();
        if (wv == 0) {
            int w = (lane < 16) ? shW[lane] : 0;
            for (int d = 1; d < 16; d <<= 1) {
                int u = __shfl_up(w, d);
                if (lane >= d) w += u;
            }
            if (lane < 16) shW[lane] = w;
        }
        __syncthreads();
        int woff = (wv > 0) ? shW[wv - 1] : 0;
        int incl = v + woff;
        int excl = incl - s;
        for (int k = 0; k < 20; ++k) {
            int i = base + k;
            if (i < N_) { int o = excl + loc[k]; off[i] = o; cur[i] = o; }
        }
        if (t == 1023) off[N_] = incl;
    } else {
        if (t < 64) {
            int v0 = bcnt[t];
            int v = v0;
            for (int d = 1; d < 64; d <<= 1) {
                int u = __shfl_up(v, d);
                if (t >= d) v += u;
            }
            boff[t] = v - v0; bcur[t] = v - v0;
            if (t == 63) boff[64] = v;
        }
    }
}

// ================= fused fills =================
__global__ __launch_bounds__(256) void k_fills(const int* __restrict__ eidx,
                                               int* __restrict__ cur, int* __restrict__ rank,
                                               const int* __restrict__ batch,
                                               int* __restrict__ bcur, int* __restrict__ bperm) {
    int bid = blockIdx.x, t = threadIdx.x;
    if (bid < 1250) {
        int e = bid * 256 + t;
        rank[e] = atomicAdd(&cur[eidx[E_ + e]], 1);
    } else {
        int n = (bid - 1250) * 256 + t;
        if (n < N_) {
            int p = atomicAdd(&bcur[batch[n]], 1);
            bperm[p] = n;
        }
    }
}

// ================= main edge kernel: 32 edges/wave, 8 blocks/CU target =================
template <bool STORE>
__global__ __launch_bounds__(256, 8) void k_edge(
    const unsigned short* __restrict__ efp, const int* __restrict__ eidx,
    const int* __restrict__ rank,
    const float* __restrict__ x, float* __restrict__ agg, unsigned short* __restrict__ msg,
    const unsigned short* __restrict__ w1r, const float* __restrict__ b1,
    const unsigned short* __restrict__ w2r, const float* __restrict__ b2,
    const unsigned short* __restrict__ w3r, const float* __restrict__ b3) {
    __shared__ float s_b3[1024];                            // 4 KB (block-shared)
    __shared__ __align__(16) unsigned short s_h[4][640];    // per-wave transpose buf, stride 40
    __shared__ __align__(16) unsigned short s_x[4][2][640]; // per-wave bf16 x tiles, stride 40

    const int t = threadIdx.x;
    for (int k = t; k < 1024; k += 256) s_b3[k] = b3[k];

    const int wave = t >> 6, lane = t & 63;
    const int q = lane >> 4, e = lane & 15;
    const int ebase = (blockIdx.x * 4 + wave) * 32;

    // stage x[src] tiles as bf16 (per-wave LDS), one 16B store per lane
    for (int g = 0; g < 2; ++g) {
        int srce = eidx[ebase + g * 16 + e];
        const float* xp = x + srce * 32 + q * 8;
        F4 xa, xb2;
        xa.v = *(const f4*)xp;
        xb2.v = *(const f4*)(xp + 4);
        u4 P;
        P[0] = pk2(xa.f[0], xa.f[1]);
        P[1] = pk2(xa.f[2], xa.f[3]);
        P[2] = pk2(xb2.f[0], xb2.f[1]);
        P[3] = pk2(xb2.f[2], xb2.f[3]);
        *(u4*)&s_x[wave][g][e * 40 + q * 8] = P;  // byte offset e*80+q*16, 16B-aligned
    }

    // loop-invariant W1^T / W2^T fragments (pre-repacked) + bias regs
    U8 w1f[2], w2f[2];
    float b1v[2][4], b2v[2][4];
    for (int tau = 0; tau < 2; ++tau) {
        w1f[tau].u = *(const u4*)(w1r + tau * 512 + lane * 8);
        w2f[tau].u = *(const u4*)(w2r + tau * 512 + lane * 8);
        for (int r = 0; r < 4; ++r) {
            b1v[tau][r] = b1[tau * 16 + q * 4 + r];
            b2v[tau][r] = b2[tau * 16 + q * 4 + r];
        }
    }

    const f4 z4 = {0.f, 0.f, 0.f, 0.f};
    short8 h2f[2];

    // per-g MLP: within-wave LDS traffic only -> wave-local waits
    for (int g = 0; g < 2; ++g) {
        U8 ef;
        if (q == 0) ef.u = *(const u4*)(efp + (size_t)(ebase + g * 16 + e) * 8);
        else { u4 zz = {0u, 0u, 0u, 0u}; ef.u = zz; }

        f4 c0 = MFMA_B16(w1f[0].v, ef.v, z4);
        f4 c1 = MFMA_B16(w1f[1].v, ef.v, z4);
        uint2 pkw;
        pkw.x = pk2(fmaxf(c0[0] + b1v[0][0], 0.f), fmaxf(c0[1] + b1v[0][1], 0.f));
        pkw.y = pk2(fmaxf(c0[2] + b1v[0][2], 0.f), fmaxf(c0[3] + b1v[0][3], 0.f));
        *(uint2*)&s_h[wave][e * 40 + q * 4] = pkw;
        pkw.x = pk2(fmaxf(c1[0] + b1v[1][0], 0.f), fmaxf(c1[1] + b1v[1][1], 0.f));
        pkw.y = pk2(fmaxf(c1[2] + b1v[1][2], 0.f), fmaxf(c1[3] + b1v[1][3], 0.f));
        *(uint2*)&s_h[wave][e * 40 + 16 + q * 4] = pkw;
        WAVE_LDS_WAIT();
        short8 h1f = *(const short8*)&s_h[wave][e * 40 + q * 8];
        c0 = MFMA_B16(w2f[0].v, h1f, z4);
        c1 = MFMA_B16(w2f[1].v, h1f, z4);
        pkw.x = pk2(fmaxf(c0[0] + b2v[0][0], 0.f), fmaxf(c0[1] + b2v[0][1], 0.f));
        pkw.y = pk2(fmaxf(c0[2] + b2v[0][2], 0.f), fmaxf(c0[3] + b2v[0][3], 0.f));
        *(uint2*)&s_h[wave][e * 40 + q * 4] = pkw;
        pkw.x = pk2(fmaxf(c1[0] + b2v[1][0], 0.f), fmaxf(c1[1] + b2v[1][1], 0.f));
        pkw.y = pk2(fmaxf(c1[2] + b2v[1][2], 0.f), fmaxf(c1[3] + b2v[1][3], 0.f));
        *(uint2*)&s_h[wave][e * 40 + 16 + q * 4] = pkw;
        WAVE_LDS_WAIT();
        h2f[g] = *(const short8*)&s_h[wave][e * 40 + q * 8];
        WAVE_LDS_WAIT();
    }

    __syncthreads();  // s_b3 visibility

    F4 macc[2][2];
    macc[0][0].v = z4; macc[0][1].v = z4; macc[1][0].v = z4; macc[1][1].v = z4;

#pragma unroll 4
    for (int h = 0; h < 32; ++h) {
        short8 a0 = *(const short8*)(w3r + h * 1024 + lane * 8);
        short8 a1 = *(const short8*)(w3r + h * 1024 + 512 + lane * 8);
        f4 ci0 = *(const f4*)&s_b3[h * 32 + q * 4];
        f4 ci1 = *(const f4*)&s_b3[h * 32 + 16 + q * 4];
        for (int g = 0; g < 2; ++g) {
            float xv = bs2f(s_x[wave][g][e * 40 + h]);
            F4 d0, d1, m0, m1;
            d0.v = MFMA_B16(a0, h2f[g], ci0);
            d1.v = MFMA_B16(a1, h2f[g], ci1);
            for (int r = 0; r < 4; ++r) {
                m0.f[r] = fmaxf(d0.f[r], 0.f);
                m1.f[r] = fmaxf(d1.f[r], 0.f);
            }
            f2v xv2 = {xv, xv};
            macc[g][0].h[0] = __builtin_elementwise_fma(m0.h[0], xv2, macc[g][0].h[0]);
            macc[g][0].h[1] = __builtin_elementwise_fma(m0.h[1], xv2, macc[g][0].h[1]);
            macc[g][1].h[0] = __builtin_elementwise_fma(m1.h[0], xv2, macc[g][1].h[0]);
            macc[g][1].h[1] = __builtin_elementwise_fma(m1.h[1], xv2, macc[g][1].h[1]);
        }
    }

    if (STORE) {
        for (int g = 0; g < 2; ++g) {
            int rk = rank[ebase + g * 16 + e];
            unsigned short* mp = msg + (size_t)rk * 32 + q * 4;
            for (int p = 0; p < 2; ++p) {
                uint2 m;
                m.x = pk2(macc[g][p].f[0], macc[g][p].f[1]);
                m.y = pk2(macc[g][p].f[2], macc[g][p].f[3]);
                *(uint2*)(mp + p * 16) = m;
            }
        }
    } else {
        for (int g = 0; g < 2; ++g) {
            int dste = eidx[E_ + ebase + g * 16 + e];
            float* ap = agg + dste * 32 + q * 4;
            for (int p = 0; p < 2; ++p)
                for (int r = 0; r < 4; ++r)
                    atomicAdd(ap + p * 16 + r, macc[g][p].f[r]);
        }
    }
}

// ================= gather: one wave per node, contiguous u4 streaming =================
__global__ __launch_bounds__(256) void k_gather(const unsigned short* __restrict__ msg,
                                                const int* __restrict__ off,
                                                const float* __restrict__ cb,
                                                float* __restrict__ x) {
    int wave = threadIdx.x >> 6, lane = threadIdx.x & 63;
    int n = blockIdx.x * 4 + wave;
    if (n >= N_) return;
    int j0 = off[n], j1 = off[n + 1];
    const unsigned short* base = msg + (size_t)j0 * 32;
    int nchunk = (j1 - j0) * 4;  // 16B chunks; row=64B so always whole chunks
    float a[8] = {0.f, 0.f, 0.f, 0.f, 0.f, 0.f, 0.f, 0.f};
    for (int it = lane; it < nchunk; it += 64) {
        u4 v = *(const u4*)(base + it * 8);
        for (int m = 0; m < 4; ++m) {
            unsigned int w = v[m];
            a[2 * m]     += __uint_as_float(w << 16);
            a[2 * m + 1] += __uint_as_float(w & 0xffff0000u);
        }
    }
    for (int d = 4; d < 64; d <<= 1)
        for (int m = 0; m < 8; ++m)
            a[m] += __shfl_xor(a[m], d);
    if (lane < 4) {
        int c0 = lane * 8;
        float* xp = x + n * 32 + c0;
        F4 xa, xb2;
        xa.v = *(const f4*)xp;
        xb2.v = *(const f4*)(xp + 4);
        for (int i = 0; i < 4; ++i) {
            xa.f[i]  += fmaxf(a[i] + cb[c0 + i], 0.f);
            xb2.f[i] += fmaxf(a[4 + i] + cb[c0 + 4 + i], 0.f);
        }
        *(f4*)xp = xa.v;
        *(f4*)(xp + 4) = xb2.v;
    }
}

__device__ __forceinline__ float selu_(float v) {
    return 1.0507009873554805f * (v > 0.f ? v : 1.6732632423543772f * (expf(v) - 1.f));
}

// ================= fused pooling (32 slots) + head MLP + IDX gather =================
__global__ __launch_bounds__(1024) void k_pool_head(const float* __restrict__ x,
                                                    const int* __restrict__ boff,
                                                    const int* __restrict__ bperm,
                                                    const float* __restrict__ W1, const float* __restrict__ b1,
                                                    const float* __restrict__ W2, const float* __restrict__ b2,
                                                    const float* __restrict__ W3, const float* __restrict__ b3,
                                                    const float* __restrict__ W4, const float* __restrict__ b4,
                                                    float* __restrict__ out) {
    __shared__ float sp[32][32];
    __shared__ float s0[32], s1[128], s2[64], s3[32], s4[21];
    int b = blockIdx.x, t = threadIdx.x, c = t & 31, slot = t >> 5;
    int j0 = boff[b], j1 = boff[b + 1];
    float a = 0.f;
    for (int j = j0 + slot; j < j1; j += 32)
        a += x[bperm[j] * 32 + c];
    sp[slot][c] = a;
    __syncthreads();
    if (t < 32) {
        float s = 0.f;
        for (int k = 0; k < 32; ++k) s += sp[k][t];
        s0[t] = s / fmaxf((float)(j1 - j0), 1.f);
    }
    __syncthreads();
    if (t < 128) {
        float v = b1[t];
        for (int cc = 0; cc < 32; ++cc) v += s0[cc] * W1[cc * 128 + t];
        s1[t] = selu_(v);
    }
    __syncthreads();
    if (t < 64) {
        float v = b2[t];
        for (int cc = 0; cc < 128; ++cc) v += s1[cc] * W2[cc * 64 + t];
        s2[t] = selu_(v);
    }
    __syncthreads();
    if (t < 32) {
        float v = b3[t];
        for (int cc = 0; cc < 64; ++cc) v += s2[cc] * W3[cc * 32 + t];
        s3[t] = selu_(v);
    }
    __syncthreads();
    if (t < 21) {
        float v = b4[t];
        for (int cc = 0; cc < 32; ++cc) v += s3[cc] * W4[cc * 21 + t];
        s4[t] = v;
    }
    __syncthreads();
    if (t < 36) out[b * 36 + t] = s4[c_IDX[t]];
}

// ================= fallback helpers (atomic path) =================
__global__ __launch_bounds__(256) void k_init_fb(const float* __restrict__ na,
                                                 const float* __restrict__ eW,
                                                 const float* __restrict__ eb,
                                                 float* __restrict__ x, float* __restrict__ agg) {
    int tid = blockIdx.x * 256 + threadIdx.x;
    int n = tid >> 5, c = tid & 31;
    x[tid] = na[n] * eW[c] + eb[c];
    agg[tid] = 0.f;
}

__global__ __launch_bounds__(256) void k_prep_fb(const float* __restrict__ pos,
                                                 const float* __restrict__ shifts,
                                                 const float* __restrict__ eattr,
                                                 const int* __restrict__ eidx,
                                                 unsigned short* __restrict__ efp) {
    int e = blockIdx.x * 256 + threadIdx.x;
    int s = eidx[e], d = eidx[E_ + e];
    float vx = pos[d * 3 + 0] - pos[s * 3 + 0] + shifts[e * 3 + 0];
    float vy = pos[d * 3 + 1] - pos[s * 3 + 1] + shifts[e * 3 + 1];
    float vz = pos[d * 3 + 2] - pos[s * 3 + 2] + shifts[e * 3 + 2];
    float ln = sqrtf(vx * vx + vy * vy + vz * vz);
    u4 o;
    o[0] = pk2(vx, vy);
    o[1] = pk2(vz, ln);
    o[2] = pk2(eattr[e], 0.f);
    o[3] = 0u;
    *(u4*)(efp + (size_t)e * 8) = o;
}

__global__ __launch_bounds__(256) void k_repack_fb(const float* __restrict__ w3,
                                                   unsigned short* __restrict__ w3r,
                                                   const float* __restrict__ w1,
                                                   const float* __restrict__ w2,
                                                   unsigned short* __restrict__ w1r,
                                                   unsigned short* __restrict__ w2r) {
    int tid = blockIdx.x * 256 + threadIdx.x;
    if (tid < 12288) {
        int l = tid & 63, t2 = (tid >> 6) & 63, i = tid >> 12;
        int q = l >> 4, m = l & 15;
        U8 o;
        for (int j = 0; j < 8; ++j) {
            int k = q * 8 + j;
            o.us[j] = f2bs(w3[(i * 32 + k) * 1024 + t2 * 16 + m]);
        }
        *(u4*)(w3r + (size_t)tid * 8) = o.u;
    } else if (tid < 13056) {
        int t2 = tid - 12288;
        bool isw2 = t2 >= 384;
        int idx = isw2 ? t2 - 384 : t2;
        int i = idx >> 7, tau = (idx >> 6) & 1, l = idx & 63;
        int q = l >> 4, m = l & 15;
        U8 o;
        for (int j = 0; j < 8; ++j) {
            int k = q * 8 + j;
            if (!isw2) o.us[j] = (k < 5) ? f2bs(w1[i * 160 + k * 32 + tau * 16 + m]) : (unsigned short)0;
            else       o.us[j] = f2bs(w2[i * 1024 + k * 32 + tau * 16 + m]);
        }
        unsigned short* dst = (isw2 ? w2r : w1r) + i * 1024 + tau * 512 + l * 8;
        *(u4*)dst = o.u;
    }
}

__global__ __launch_bounds__(256) void k_node(float* __restrict__ x, float* __restrict__ agg,
                                              const float* __restrict__ cb) {
    int tid = blockIdx.x * 256 + threadIdx.x;
    int c = tid & 31;
    float a = agg[tid] + cb[c];
    x[tid] += fmaxf(a, 0.f);
    agg[tid] = 0.f;
}

__global__ __launch_bounds__(256) void k_zero_pool(float* __restrict__ pooled, int* __restrict__ cnt) {
    int tid = blockIdx.x * 256 + threadIdx.x;
    if (tid < 2048) pooled[tid] = 0.f;
    else if (tid < 2112) cnt[tid - 2048] = 0;
}

__global__ __launch_bounds__(256) void k_pool(const float* __restrict__ x, const int* __restrict__ batch,
                                              float* __restrict__ pooled, int* __restrict__ cnt) {
    int tid = blockIdx.x * 256 + threadIdx.x;
    int n = tid >> 5, c = tid & 31;
    int b = batch[n];
    atomicAdd(&pooled[b * 32 + c], x[tid]);
    if (c == 0) atomicAdd(&cnt[b], 1);
}

__global__ __launch_bounds__(128) void k_head(const float* __restrict__ pooled, const int* __restrict__ cnt,
                                              const float* __restrict__ W1, const float* __restrict__ b1,
                                              const float* __restrict__ W2, const float* __restrict__ b2,
                                              const float* __restrict__ W3, const float* __restrict__ b3,
                                              const float* __restrict__ W4, const float* __restrict__ b4,
                                              float* __restrict__ out) {
    __shared__ float s0[32], s1[128], s2[64], s3[32], s4[21];
    int b = blockIdx.x, t = threadIdx.x;
    if (t < 32) s0[t] = pooled[b * 32 + t] / fmaxf((float)cnt[b], 1.f);
    __syncthreads();
    {
        float a = b1[t];
        for (int c = 0; c < 32; ++c) a += s0[c] * W1[c * 128 + t];
        s1[t] = selu_(a);
    }
    __syncthreads();
    if (t < 64) {
        float a = b2[t];
        for (int c = 0; c < 128; ++c) a += s1[c] * W2[c * 64 + t];
        s2[t] = selu_(a);
    }
    __syncthreads();
    if (t < 32) {
        float a = b3[t];
        for (int c = 0; c < 64; ++c) a += s2[c] * W3[c * 32 + t];
        s3[t] = selu_(a);
    }
    __syncthreads();
    if (t < 21) {
        float a = b4[t];
        for (int c = 0; c < 32; ++c) a += s3[c] * W4[c * 21 + t];
        s4[t] = a;
    }
    __syncthreads();
    if (t < 36) out[b * 36 + t] = s4[c_IDX[t]];
}

extern "C" void kernel_launch(void* const* d_in, const int* in_sizes, int n_in,
                              void* d_out, int out_size, void* d_ws, size_t ws_size,
                              hipStream_t stream) {
    const float* na     = (const float*)d_in[0];
    const float* pos    = (const float*)d_in[1];
    const float* shifts = (const float*)d_in[2];
    const float* eattr  = (const float*)d_in[3];
    const int*   eidx   = (const int*)d_in[4];
    const int*   batch  = (const int*)d_in[5];
    const float* embW   = (const float*)d_in[6];
    const float* embB   = (const float*)d_in[7];
    const float* eW1    = (const float*)d_in[8];
    const float* eb1    = (const float*)d_in[9];
    const float* eW2    = (const float*)d_in[10];
    const float* eb2    = (const float*)d_in[11];
    const float* eW3    = (const float*)d_in[12];
    const float* eb3    = (const float*)d_in[13];
    const float* cvb    = (const float*)d_in[14];
    const float* hW1    = (const float*)d_in[15];
    const float* hb1    = (const float*)d_in[16];
    const float* hW2    = (const float*)d_in[17];
    const float* hb2    = (const float*)d_in[18];
    const float* hW3    = (const float*)d_in[19];
    const float* hb3    = (const float*)d_in[20];
    const float* hW4    = (const float*)d_in[21];
    const float* hb4    = (const float*)d_in[22];

    // layout: x | deg | bcnt | off | cur | rank | boff | bcur | bperm | efp | w3r | w1r | w2r | msg
    const size_t need_csr = (size_t)640000 * 4
                          + (size_t)(20000 + 64 + 20004 + 20000 + 320000 + 68 + 64 + 20000) * 4
                          + ((size_t)E_ * 8 + 98304 + 3072 + 3072 + (size_t)E_ * 32) * 2;

    if (ws_size >= need_csr) {
        char* ws = (char*)d_ws;
        float* x      = (float*)ws;                              // 640000 f32
        int*   deg    = (int*)(x + 640000);                      // 20000
        int*   bcnt   = deg + 20000;                             // 64 (contiguous with deg)
        int*   off    = bcnt + 64;                               // 20001 (pad 20004)
        int*   cur    = off + 20004;                             // 20000
        int*   rank   = cur + 20000;                             // 320000
        int*   boff   = rank + 320000;                           // 65 (pad 68)
        int*   bcur   = boff + 68;                               // 64
        int*   bperm  = bcur + 64;                               // 20000
        unsigned short* efp = (unsigned short*)(bperm + 20000);  // E_*8 bf16
        unsigned short* w3r = efp + (size_t)E_ * 8;              // 98304 bf16
        unsigned short* w1r = w3r + 98304;                       // 3072 bf16
        unsigned short* w2r = w1r + 3072;                        // 3072 bf16
        unsigned short* msg = w2r + 3072;                        // E_*32 bf16

        hipMemsetAsync(deg, 0, (20000 + 64) * sizeof(int), stream);  // deg + bcnt
        k_setup<<<2005, 256, 0, stream>>>(na, embW, embB, x, deg, bcnt,
                                          pos, shifts, eattr, eidx, efp,
                                          eW3, w3r, eW1, eW2, w1r, w2r, batch);
        k_scans<<<2, 1024, 0, stream>>>(deg, off, cur, bcnt, boff, bcur);
        k_fills<<<1329, 256, 0, stream>>>(eidx, cur, rank, batch, bcur, bperm);

        for (int i = 0; i < 3; ++i) {
            k_edge<true><<<2500, 256, 0, stream>>>(efp, eidx, rank, x, nullptr, msg,
                                                   w1r + i * 1024, eb1 + i * 32,
                                                   w2r + i * 1024, eb2 + i * 32,
                                                   w3r + i * 32768, eb3 + i * 1024);
            k_gather<<<5000, 256, 0, stream>>>(msg, off, cvb + i * 32, x);
        }

        k_pool_head<<<64, 1024, 0, stream>>>(x, boff, bperm,
                                             hW1, hb1, hW2, hb2, hW3, hb3, hW4, hb4,
                                             (float*)d_out);
    } else {
        // fallback: atomic scatter path
        char* ws = (char*)d_ws;
        float* x      = (float*)ws;                           // 640000 f32
        float* agg    = x + 640000;                           // 640000 f32
        float* pooled = agg + 640000;                         // 2048 f32
        int*   cnt    = (int*)(pooled + 2048);                // 64
        unsigned short* efp = (unsigned short*)(cnt + 64);    // E_*8 bf16
        unsigned short* w3r = efp + (size_t)E_ * 8;           // 98304 bf16
        unsigned short* w1r = w3r + 98304;                    // 3072
        unsigned short* w2r = w1r + 3072;                     // 3072

        k_init_fb<<<2500, 256, 0, stream>>>(na, embW, embB, x, agg);
        k_prep_fb<<<1250, 256, 0, stream>>>(pos, shifts, eattr, eidx, efp);
        k_repack_fb<<<51, 256, 0, stream>>>(eW3, w3r, eW1, eW2, w1r, w2r);
        k_zero_pool<<<9, 256, 0, stream>>>(pooled, cnt);

        for (int i = 0; i < 3; ++i) {
            k_edge<false><<<2500, 256, 0, stream>>>(efp, eidx, nullptr, x, agg, nullptr,
                                                    w1r + i * 1024, eb1 + i * 32,
                                                    w2r + i * 1024, eb2 + i * 32,
                                                    w3r + i * 32768, eb3 + i * 1024);
            k_node<<<2500, 256, 0, stream>>>(x, agg, cvb + i * 32);
        }

        k_pool<<<2500, 256, 0, stream>>>(x, batch, pooled, cnt);
        k_head<<<64, 128, 0, stream>>>(pooled, cnt, hW1, hb1, hW2, hb2, hW3, hb3, hW4, hb4,
                                       (float*)d_out);
    }
}